// Round 10
// baseline (796.353 us; speedup 1.0000x reference)
//
#include <hip/hip_runtime.h>
#include <math.h>

// ---------------------------------------------------------------------------
// CapsuleNet forward (round 27): tail fixes, prim frozen at round-24 floor.
//  (1) conv1: epilogue now stages the 128x128 output tile in LDS (reusing
//      Al/Bw space after compute, stride 132 halves for bank spread) and
//      copies out linearly -> 256B write segments instead of 32B granules
//      (104 MB hhi stream, ~2x write-efficiency).
//  (2) prep_k: C-zeroing via float4 grid-stride (1152 blocks, was 18432
//      scalar-dword blocks).
// Frozen: prim (301us floor: dbuf gload_lds + setprio; 7 mechanisms tried),
// conv1 staging/MFMA (r22/26), priors/routing two-phase (r6/12/14; r9 data:
// L3 absorbs ~half the priors round-trip -> fusion upside limited),
// dec1/dec_gemm (r12).
// ---------------------------------------------------------------------------

typedef _Float16 h16;
typedef h16 frag8 __attribute__((ext_vector_type(8)));    // 8 halves = 16 B
typedef h16 h16x4 __attribute__((ext_vector_type(4)));    // 4 halves = 8 B
typedef float f32x4 __attribute__((ext_vector_type(4)));

// workspace layout (BYTE offsets).
#define OFFB_HHI   0L             // 52428800 halves = 104857600 B
#define OFFB_WTHI  209715200L     // 5308416 halves = 10616832 B
#define OFFB_WT1   230948864L     // w1t: 24576 halves = 49152 B
#define OFFB_C     231031808L     // 4718592 floats -> end 249906176
#define WS_BYTES   249906176L
// aliased into dead h region after prim_gemm:
#define OFFB_PRI   0L             // 94371840 halves = 188743680 B (priors fp16)
#define OFFB_UT    188743680L     // 4718592 halves = 9437184 B -> OK
// aliased into dead wt region after prim_gemm:
#define OFFB_V     209715200L     // 81920 floats
#define OFFB_D1    210370560L     // 262144 floats
#define OFFB_D2    211419136L     // 524288 floats -> 213516288 OK

// async global->LDS, 16 B per lane. LDS dest must be lane-linear:
// lane i of a wave writes base + i*16 B.
#define GLL16(gp, lp)                                                        \
    __builtin_amdgcn_global_load_lds(                                        \
        (const __attribute__((address_space(1))) void*)(gp),                 \
        (__attribute__((address_space(3))) void*)(lp), 16, 0, 0)

// --------------------------------------------------------------------------
// prep: blocks 0..95: w1t[oc][96] fp16 (k-padded); 96..351: prim B^T fp16;
// 352..1503: zero C via float4 (294912 float4/pass, 4 passes).
__global__ __launch_bounds__(256) void prep_k(const float* __restrict__ w1,
                                              const float* __restrict__ pw,
                                              h16* __restrict__ w1t,
                                              h16* __restrict__ whi,
                                              float* __restrict__ C) {
    __shared__ float s[2592];
    int bx = blockIdx.x, tid = threadIdx.x;
    if (bx < 96) {
        int k = bx, oc = tid;
        w1t[(long)oc * 96 + k] = (k < 81) ? (h16)w1[oc * 81 + k] : (h16)0.f;
    } else if (bx < 352) {
        int oc = bx - 96;
        long src0 = (long)oc * 20736, dst0 = src0;
        for (int ch = 0; ch < 8; ++ch) {
            int ic0 = ch * 32;
            __syncthreads();
            for (int e = tid; e < 2592; e += 256) s[e] = pw[src0 + ic0 * 81 + e];
            __syncthreads();
            for (int e = tid; e < 2592; e += 256) {
                int tap = e >> 5, icf = e & 31;
                whi[dst0 + tap * 256 + ic0 + icf] = (h16)s[icf * 81 + tap];
            }
        }
    } else {
        // 1152 blocks x 256 thr x 4 float4 = 4718592 floats exact
        float4* C4 = (float4*)C;
        long i = (long)(bx - 352) * 256 + tid;
        float4 z = make_float4(0.f, 0.f, 0.f, 0.f);
#pragma unroll
        for (int p = 0; p < 4; ++p) C4[i + (long)p * 294912] = z;
    }
}

// --------------------------------------------------------------------------
// conv1 as MFMA implicit-im2col GEMM. Grid 3200: nt = bx&1, mt = bx>>1.
// r22: pair-vectorized im2col + operand-swapped MFMA. r26: 3 blocks/CU +
// vectorized B-stage + setprio. r27: LDS-staged coalesced epilogue.
#define CLDK 104
#define TLD 132   // output-tile LDS stride (halves): 264B = 33x8B, bank-spread
__global__ __launch_bounds__(256, 3) void conv1_mfma(const float* __restrict__ x,
                                                     const h16* __restrict__ w1t,
                                                     const float* __restrict__ bias,
                                                     h16* __restrict__ hhi) {
    // single pool: Al = [0, 13312), Bw = [13312, 26624). Output tile T
    // (128 x TLD = 16896 halves) aliases the pool after compute.
    __shared__ h16 smem[2 * 128 * CLDK];
    h16* Al = smem;
    h16* Bw = smem + 128 * CLDK;
    int tid = threadIdx.x;
    int bx = blockIdx.x;
    int nt = bx & 1, mt = bx >> 1;
    int n0 = nt * 128;

    // B stage: thread = (oc = tid>>1, half = tid&1) copies 48 contiguous
    // halves (96 B) as 6 x 16B vector ops. No division, coalesced.
    {
        int oc = tid >> 1, half = tid & 1;
        const frag8* src = (const frag8*)(w1t + (long)(n0 + oc) * 96 + half * 48);
        frag8* dst = (frag8*)(&Bw[oc * CLDK + half * 48]);
#pragma unroll
        for (int v = 0; v < 6; ++v) dst[v] = src[v];
    }
    // A stage: one (ml, ky) pair per step -> 9 contiguous x floats.
    for (int p = tid; p < 128 * 9; p += 256) {
        int ml = p / 9, ky = p - (p / 9) * 9;
        int m = mt * 128 + ml;
        int b = m / 400, pix = m - b * 400;
        int oy = pix / 20, ox = pix - oy * 20;
        const float* xs = x + (long)b * 784 + (oy + ky) * 28 + ox;
        h16* dst = &Al[ml * CLDK + ky * 9];
#pragma unroll
        for (int kx = 0; kx < 9; ++kx) dst[kx] = (h16)xs[kx];
    }
    // zero the k = 81..95 pad (MFMA reads through k=95).
    for (int e = tid; e < 128 * 16; e += 256) {
        int ml = e >> 4, kz = 81 + (e & 15);
        if (kz < 96) Al[ml * CLDK + kz] = (h16)0.f;
    }
    __syncthreads();

    int wave = tid >> 6;
    int wm = wave >> 1, wn = wave & 1;
    int lane = tid & 63;
    int lm = lane & 15, quad = lane >> 4;

    f32x4 acc[4][4];   // acc[ni][mi]: D rows = oc (quad*4+r), cols = m (lm)
#pragma unroll
    for (int i = 0; i < 4; ++i)
#pragma unroll
        for (int j = 0; j < 4; ++j) acc[i][j] = (f32x4){0.f, 0.f, 0.f, 0.f};

#pragma unroll
    for (int ks = 0; ks < 3; ++ks) {
        int kc = ks * 32 + quad * 8;
        frag8 af[4], bf[4];
#pragma unroll
        for (int mi = 0; mi < 4; ++mi)
            af[mi] = *(const frag8*)&Al[(wm * 64 + mi * 16 + lm) * CLDK + kc];
#pragma unroll
        for (int ni = 0; ni < 4; ++ni)
            bf[ni] = *(const frag8*)&Bw[(wn * 64 + ni * 16 + lm) * CLDK + kc];
        // operand swap: first operand's lm-space (oc) -> D rows (quad*4+r),
        // second operand's lm-space (m) -> D cols (lm).
        __builtin_amdgcn_s_setprio(1);
#pragma unroll
        for (int ni = 0; ni < 4; ++ni)
#pragma unroll
            for (int mi = 0; mi < 4; ++mi)
                acc[ni][mi] = __builtin_amdgcn_mfma_f32_16x16x32_f16(
                    bf[ni], af[mi], acc[ni][mi], 0, 0, 0);
        __builtin_amdgcn_s_setprio(0);
    }

    // epilogue (r27): bias+relu -> LDS tile T[128m][TLD] (aliases Al/Bw),
    // then linear copy-out: thread owns 64 contiguous oc of one m-row ->
    // 128B runs, 256B segments per row pair of threads.
    __syncthreads();                      // all frag reads of Al/Bw done
    h16* T = smem;                        // 128*TLD = 16896 <= 26624 halves
#pragma unroll
    for (int ni = 0; ni < 4; ++ni) {
        int ocl = wn * 64 + ni * 16 + quad * 4;        // oc within tile
        float4 bv = *(const float4*)(bias + n0 + ocl);
#pragma unroll
        for (int mi = 0; mi < 4; ++mi) {
            int ml = wm * 64 + mi * 16 + lm;           // m within tile
            h16x4 o;
            o[0] = (h16)fmaxf(acc[ni][mi][0] + bv.x, 0.f);
            o[1] = (h16)fmaxf(acc[ni][mi][1] + bv.y, 0.f);
            o[2] = (h16)fmaxf(acc[ni][mi][2] + bv.z, 0.f);
            o[3] = (h16)fmaxf(acc[ni][mi][3] + bv.w, 0.f);
            *(h16x4*)&T[ml * TLD + ocl] = o;
        }
    }
    __syncthreads();
    {
        int row = tid >> 1, half = tid & 1;            // 128 rows x 2 halves
        const h16* src = &T[row * TLD + half * 64];
        h16* dst = hhi + (long)(mt * 128 + row) * 256 + n0 + half * 64;
#pragma unroll
        for (int v = 0; v < 8; ++v) {
            h16x4 a0 = *(const h16x4*)(src + v * 8);
            h16x4 a1 = *(const h16x4*)(src + v * 8 + 4);
            frag8 f;
            f[0] = a0[0]; f[1] = a0[1]; f[2] = a0[2]; f[3] = a0[3];
            f[4] = a1[0]; f[5] = a1[1]; f[6] = a1[2]; f[7] = a1[3];
            *(frag8*)(dst + v * 8) = f;
        }
    }
}

// --------------------------------------------------------------------------
// prim conv MFMA GEMM (round-24 EXACT, 297-301 us floor): BM=128 BN=128
// BK=32, split-K x8 (kt = bx&7 -> XCD-pinned B slice). global_load_lds
// dwordx4 into double-buffered LINEAR LDS [128][32]; one barrier per K-step;
// setprio(1) around MFMA cluster. Atomic accumulate into zeroed C.
__global__ __launch_bounds__(256, 4) void prim_gemm_mfma(
        const h16* __restrict__ Ahi, const h16* __restrict__ Bhi,
        float* __restrict__ C) {
    __shared__ __align__(16) h16 As[2][128 * 32];
    __shared__ __align__(16) h16 Bs[2][128 * 32];
    int tid = threadIdx.x;
    int bx = blockIdx.x;                  // 2304 blocks
    int kt = bx & 7;
    int nt = (bx >> 3) & 1;
    int mt = bx >> 4;                     // 0..143
    int n0 = nt * 128;
    int kb0 = kt * 81;

    int wave = tid >> 6;
    int wm = wave >> 1, wn = wave & 1;
    int lane = tid & 63;
    int lm = lane & 15, quad = lane >> 4;

    // staging geometry: thread t, chunk q in {0,1} covers LDS halves
    // [t*8 + q*2048, +8)  ->  row r = (t>>2) + q*64, col c = (t&3)*8.
    int c0 = (tid & 3) * 8;
    int r0 = tid >> 2;
    long abase0, abase1, bbase0, bbase1;
    {
        int m = mt * 128 + r0;
        int b = m / 36, pos = m - b * 36;
        int oy = pos / 6, ox = pos - oy * 6;
        abase0 = ((long)(b * 20 + 2 * oy) * 20 + 2 * ox) * 256 + c0;
        m = mt * 128 + r0 + 64;
        b = m / 36; pos = m - b * 36;
        oy = pos / 6; ox = pos - oy * 6;
        abase1 = ((long)(b * 20 + 2 * oy) * 20 + 2 * ox) * 256 + c0;
        bbase0 = (long)(n0 + r0) * 20736 + c0;
        bbase1 = (long)(n0 + r0 + 64) * 20736 + c0;
    }
    h16* la = &As[0][tid * 8];
    h16* lb = &Bs[0][tid * 8];

    auto stage = [&](int buf, int kb) {
        // wave-uniform K-step decode (lands in SGPRs)
        int tap = kb >> 3;
        int ic0 = (kb & 7) << 5;
        int ky = tap / 9, kx = tap - ky * 9;
        long aoff = (long)(ky * 20 + kx) * 256 + ic0;
        long boff = (long)kb * 32;
        long lo = (long)buf * 4096;       // halves per buffer
        GLL16(Ahi + abase0 + aoff, la + lo);
        GLL16(Ahi + abase1 + aoff, la + lo + 2048);
        GLL16(Bhi + bbase0 + boff, lb + lo);
        GLL16(Bhi + bbase1 + boff, lb + lo + 2048);
    };

    f32x4 acc[4][4];
#pragma unroll
    for (int i = 0; i < 4; ++i)
#pragma unroll
        for (int j = 0; j < 4; ++j) acc[i][j] = (f32x4){0.f, 0.f, 0.f, 0.f};

    stage(0, kb0);
    for (int it = 0; it < 81; ++it) {
        int cur = it & 1;
        // one barrier per K-step: drains vmcnt (buf[cur] staged) and lgkm
        // (prev iter's ds_reads of buf[cur^1] done before we overwrite it).
        __syncthreads();
        if (it + 1 < 81) stage(cur ^ 1, kb0 + it + 1);

        frag8 ah[4], bh[4];
#pragma unroll
        for (int mi = 0; mi < 4; ++mi) {
            int row = wm * 64 + mi * 16 + lm;
            ah[mi] = *(const frag8*)&As[cur][row * 32 + quad * 8];
        }
#pragma unroll
        for (int ni = 0; ni < 4; ++ni) {
            int col = wn * 64 + ni * 16 + lm;
            bh[ni] = *(const frag8*)&Bs[cur][col * 32 + quad * 8];
        }
        __builtin_amdgcn_s_setprio(1);
#pragma unroll
        for (int mi = 0; mi < 4; ++mi)
#pragma unroll
            for (int ni = 0; ni < 4; ++ni)
                acc[mi][ni] = __builtin_amdgcn_mfma_f32_16x16x32_f16(
                    ah[mi], bh[ni], acc[mi][ni], 0, 0, 0);
        __builtin_amdgcn_s_setprio(0);
    }

#pragma unroll
    for (int ni = 0; ni < 4; ++ni) {
        int n = n0 + wn * 64 + ni * 16 + lm;
#pragma unroll
        for (int mi = 0; mi < 4; ++mi) {
            int m = mt * 128 + wm * 64 + mi * 16 + quad * 4;
#pragma unroll
            for (int r = 0; r < 4; ++r)
                atomicAdd(&C[(long)(m + r) * 256 + n], acc[mi][ni][r]);
        }
    }
}

// --------------------------------------------------------------------------
// squash: C[(b*36+pos)][256] (+bias) -> ut[n][b][8] fp16, n = ci*36+pos.
__global__ void squash_k(const float* __restrict__ C,
                         const float* __restrict__ bias,
                         h16* __restrict__ ut) {
    int t = blockIdx.x * 256 + threadIdx.x;          // 589824 exact
    int row = t >> 5;                                 // (b*36+pos)
    int ci = t & 31;
    int b = row / 36, pos = row - b * 36;
    const float* src = C + (long)row * 256 + ci;
    float v[8]; float sn = 0.f;
#pragma unroll
    for (int i = 0; i < 8; ++i) {
        v[i] = src[i * 32] + bias[ci + i * 32];
        sn = fmaf(v[i], v[i], sn);
    }
    float scale = (sn / (1.f + sn)) / sqrtf(sn);
    frag8 o;
#pragma unroll
    for (int i = 0; i < 8; ++i) o[i] = (h16)(v[i] * scale);
    *(frag8*)(ut + ((long)(ci * 36 + pos) * 512 + b) * 8) = o;
}

// --------------------------------------------------------------------------
// Phase A: priors[c,b,n,:16] = ut[n,b,:8] @ rw[c,n,:8,:16], fp16 out.
__global__ __launch_bounds__(256) void priors_k(const h16* __restrict__ ut,
                                                const float* __restrict__ rw,
                                                h16* __restrict__ priors) {
    int bid = blockIdx.x;                 // 1440 = 10 c * 144 n-groups
    int c = bid / 144, ng = bid - c * 144;
    int n0 = ng * 8;
    __shared__ float w[8][132];
    int tid = threadIdx.x;
    for (int e = tid; e < 1024; e += 256)
        w[e >> 7][e & 127] = rw[((long)c * 1152 + n0 + (e >> 7)) * 128 + (e & 127)];
    __syncthreads();
    int nl = tid & 7, bl = tid >> 3;      // bl 0..31
    int n = n0 + nl;
    for (int ch = 0; ch < 16; ++ch) {
        int b = ch * 32 + bl;
        frag8 uv = *(const frag8*)(ut + ((long)n * 512 + b) * 8);
        float uu[8];
#pragma unroll
        for (int i = 0; i < 8; ++i) uu[i] = (float)uv[i];
        float o[16];
#pragma unroll
        for (int j = 0; j < 16; ++j) o[j] = 0.f;
#pragma unroll
        for (int i = 0; i < 8; ++i)
#pragma unroll
            for (int j = 0; j < 16; ++j)
                o[j] = fmaf(uu[i], w[nl][i * 16 + j], o[j]);
        frag8 p0, p1;
#pragma unroll
        for (int j = 0; j < 8; ++j) { p0[j] = (h16)o[j]; p1[j] = (h16)o[j + 8]; }
        h16* dst = priors + ((long)(c * 512 + b) * 1152 + n) * 16;
        *(frag8*)dst = p0;
        *(frag8*)(dst + 8) = p1;
    }
}

// --------------------------------------------------------------------------
// Phase B: 3-iter routing. Block per (c,b). Iteration 0 uses the exact
// uniform-softmax shortcut (initial logits identically 0 -> probs = 1/1152).
__global__ __launch_bounds__(384) void routing2_k(const h16* __restrict__ priors,
                                                  float* __restrict__ vbuf) {
    int c = blockIdx.x >> 9;
    int b = blockIdx.x & 511;
    int tid = threadIdx.x;
    int wid = tid >> 6;
    int lane = tid & 63;
    __shared__ float wred[6][20];

    float pr[3][16];
#pragma unroll
    for (int r = 0; r < 3; ++r) {
        int n = tid + r * 384;
        const h16* pp = priors + ((long)(c * 512 + b) * 1152 + n) * 16;
        frag8 p0 = *(const frag8*)pp;
        frag8 p1 = *(const frag8*)(pp + 8);
#pragma unroll
        for (int o = 0; o < 8; ++o) { pr[r][o] = (float)p0[o]; pr[r][o + 8] = (float)p1[o]; }
    }

    float l0 = 0.f, l1 = 0.f, l2 = 0.f;
    float vout[16];

    // ---- iteration 0: probs uniform = 1/1152 ----
    {
        float red[16];
#pragma unroll
        for (int o = 0; o < 16; ++o) red[o] = pr[0][o] + pr[1][o] + pr[2][o];
#pragma unroll
        for (int o = 0; o < 16; ++o) {
#pragma unroll
            for (int m = 32; m >= 1; m >>= 1) red[o] += __shfl_xor(red[o], m);
        }
        if (lane == 0) {
#pragma unroll
            for (int o = 0; o < 16; ++o) wred[wid][o] = red[o];
        }
        __syncthreads();
        float inv = 1.f / 1152.f;
        float sn = 0.f;
        float sv[16];
#pragma unroll
        for (int o = 0; o < 16; ++o) {
            float tacc = wred[0][o];
#pragma unroll
            for (int w = 1; w < 6; ++w) tacc += wred[w][o];
            sv[o] = tacc * inv;
            sn = fmaf(sv[o], sv[o], sn);
        }
        float scale = (sn / (1.f + sn)) / sqrtf(sn);
#pragma unroll
        for (int o = 0; o < 16; ++o) vout[o] = sv[o] * scale;
        float d0 = 0.f, d1 = 0.f, d2 = 0.f;
#pragma unroll
        for (int o = 0; o < 16; ++o) {
            d0 = fmaf(pr[0][o], vout[o], d0);
            d1 = fmaf(pr[1][o], vout[o], d1);
            d2 = fmaf(pr[2][o], vout[o], d2);
        }
        l0 = d0; l1 = d1; l2 = d2;
        __syncthreads();                 // wred reused next iteration
    }

    // ---- iterations 1,2: full softmax path ----
    for (int it = 1; it < 3; ++it) {
        float lm = fmaxf(fmaxf(l0, l1), l2);
#pragma unroll
        for (int m = 32; m >= 1; m >>= 1) lm = fmaxf(lm, __shfl_xor(lm, m));
        if (lane == 0) wred[wid][17] = lm;
        __syncthreads();
        float maxv = wred[0][17];
#pragma unroll
        for (int w = 1; w < 6; ++w) maxv = fmaxf(maxv, wred[w][17]);

        float e0 = expf(l0 - maxv), e1 = expf(l1 - maxv), e2 = expf(l2 - maxv);
        float red[17];
#pragma unroll
        for (int o = 0; o < 16; ++o)
            red[o] = fmaf(e0, pr[0][o], fmaf(e1, pr[1][o], e2 * pr[2][o]));
        red[16] = e0 + e1 + e2;
#pragma unroll
        for (int o = 0; o < 17; ++o) {
#pragma unroll
            for (int m = 32; m >= 1; m >>= 1) red[o] += __shfl_xor(red[o], m);
        }
        __syncthreads();
        if (lane == 0) {
#pragma unroll
            for (int o = 0; o < 17; ++o) wred[wid][o] = red[o];
        }
        __syncthreads();
        float sv[17];
#pragma unroll
        for (int o = 0; o < 17; ++o) {
            float tacc = wred[0][o];
#pragma unroll
            for (int w = 1; w < 6; ++w) tacc += wred[w][o];
            sv[o] = tacc;
        }
        float inv = 1.f / sv[16];
        float sn = 0.f;
#pragma unroll
        for (int o = 0; o < 16; ++o) { float s = sv[o] * inv; sn = fmaf(s, s, sn); }
        float scale = (sn / (1.f + sn)) / sqrtf(sn);
#pragma unroll
        for (int o = 0; o < 16; ++o) vout[o] = sv[o] * inv * scale;

        if (it < 2) {
            float d0 = 0.f, d1 = 0.f, d2 = 0.f;
#pragma unroll
            for (int o = 0; o < 16; ++o) {
                d0 = fmaf(pr[0][o], vout[o], d0);
                d1 = fmaf(pr[1][o], vout[o], d1);
                d2 = fmaf(pr[2][o], vout[o], d2);
            }
            l0 += d0; l1 += d1; l2 += d2;
        }
    }
    if (tid < 16) vbuf[(b * 10 + c) * 16 + tid] = vout[tid];
}

// --------------------------------------------------------------------------
// dec1: fused classes/argmax/y_pred + sparse masked GEMM (K=16 of 160).
__global__ __launch_bounds__(512) void dec1_k(const float* __restrict__ vbuf,
                                              const float* __restrict__ dw1,
                                              const float* __restrict__ db1,
                                              float* __restrict__ out,
                                              float* __restrict__ d1) {
    __shared__ float sv[160];
    __shared__ float scls[10];
    __shared__ int sbest;
    int b = blockIdx.x, tid = threadIdx.x;
    if (tid < 160) sv[tid] = vbuf[b * 160 + tid];
    __syncthreads();
    if (tid < 10) {
        float sn = 0.f;
#pragma unroll
        for (int o = 0; o < 16; ++o) { float v = sv[tid * 16 + o]; sn = fmaf(v, v, sn); }
        scls[tid] = sqrtf(sn);
    }
    __syncthreads();
    if (tid == 0) {
        int best = 0; float bv = scls[0];
#pragma unroll
        for (int cc = 1; cc < 10; ++cc) if (scls[cc] > bv) { bv = scls[cc]; best = cc; }
        sbest = best;
    }
    __syncthreads();
    int best = sbest;
    if (tid < 10) {
        out[b * 10 + tid] = (tid == best) ? 1.f : 0.f;          // y_pred
        out[406528 + b * 10 + tid] = scls[tid];                 // classes
    }
    float acc = db1[tid];
    const float* wrow = dw1 + (long)best * 16 * 512;
#pragma unroll
    for (int i = 0; i < 16; ++i)
        acc = fmaf(sv[best * 16 + i], wrow[i * 512 + tid], acc);
    d1[(long)b * 512 + tid] = fmaxf(acc, 0.f);
}

// --------------------------------------------------------------------------
template <int ACT>
__global__ __launch_bounds__(256) void dec_gemm(const float* __restrict__ A,
                                                const float* __restrict__ Bw,
                                                const float* __restrict__ bias,
                                                float* __restrict__ C,
                                                int M, int N, int K) {
    __shared__ float As[16][68];
    __shared__ float Bs[16][68];
    int ntiles = (N + 63) >> 6;
    int mt = blockIdx.x / ntiles, nt = blockIdx.x - mt * ntiles;
    int m0 = mt * 64, n0 = nt * 64;
    int tid = threadIdx.x;
    int tx = tid & 15, ty = tid >> 4;
    int am = tid >> 2, ak = (tid & 3) * 4;
    int bk = tid >> 4, bn = (tid & 15) * 4;
    float acc[4][4];
#pragma unroll
    for (int i = 0; i < 4; ++i)
#pragma unroll
        for (int j = 0; j < 4; ++j) acc[i][j] = 0.f;

    for (int k0 = 0; k0 < K; k0 += 16) {
        float4 av = *(const float4*)(A + (m0 + am) * K + k0 + ak);
        float4 bv = make_float4(0.f, 0.f, 0.f, 0.f);
        if (n0 + bn < N) bv = *(const float4*)(Bw + (k0 + bk) * N + n0 + bn);
        __syncthreads();
        As[ak + 0][am] = av.x;
        As[ak + 1][am] = av.y;
        As[ak + 2][am] = av.z;
        As[ak + 3][am] = av.w;
        *(float4*)&Bs[bk][bn] = bv;
        __syncthreads();
#pragma unroll
        for (int kk = 0; kk < 16; ++kk) {
            float4 a = *(const float4*)&As[kk][ty * 4];
            float4 bb = *(const float4*)&Bs[kk][tx * 4];
            float aa[4] = {a.x, a.y, a.z, a.w};
            float bbb[4] = {bb.x, bb.y, bb.z, bb.w};
#pragma unroll
            for (int i = 0; i < 4; ++i)
#pragma unroll
                for (int j = 0; j < 4; ++j)
                    acc[i][j] = fmaf(aa[i], bbb[j], acc[i][j]);
        }
    }
#pragma unroll
    for (int i = 0; i < 4; ++i) {
        int m = m0 + ty * 4 + i;
#pragma unroll
        for (int j = 0; j < 4; ++j) {
            int n = n0 + tx * 4 + j;
            if (n < N) {
                float v = acc[i][j] + bias[n];
                if (ACT == 0) v = fmaxf(v, 0.f);
                else          v = 1.f / (1.f + expf(-v));
                C[m * N + n] = v;
            }
        }
    }
}

// --------------------------------------------------------------------------
extern "C" void kernel_launch(void* const* d_in, const int* in_sizes, int n_in,
                              void* d_out, int out_size, void* d_ws, size_t ws_size,
                              hipStream_t stream) {
    const float* x   = (const float*)d_in[0];
    const float* w1  = (const float*)d_in[1];
    const float* b1  = (const float*)d_in[2];
    const float* pw  = (const float*)d_in[3];
    const float* pb  = (const float*)d_in[4];
    const float* rw  = (const float*)d_in[5];
    const float* dw1 = (const float*)d_in[6];
    const float* db1 = (const float*)d_in[7];
    const float* dw2 = (const float*)d_in[8];
    const float* db2 = (const float*)d_in[9];
    const float* dw3 = (const float*)d_in[10];
    const float* db3 = (const float*)d_in[11];
    float* out = (float*)d_out;
    char* wsb  = (char*)d_ws;
    if (ws_size < (size_t)WS_BYTES) return;

    h16*   hhi  = (h16*)(wsb + OFFB_HHI);
    h16*   wthi = (h16*)(wsb + OFFB_WTHI);
    h16*   w1t  = (h16*)(wsb + OFFB_WT1);
    float* Cbuf = (float*)(wsb + OFFB_C);
    h16*   pri  = (h16*)(wsb + OFFB_PRI);
    h16*   ut   = (h16*)(wsb + OFFB_UT);
    float* vbuf = (float*)(wsb + OFFB_V);
    float* d1   = (float*)(wsb + OFFB_D1);
    float* d2   = (float*)(wsb + OFFB_D2);

    prep_k<<<1504, 256, 0, stream>>>(w1, pw, w1t, wthi, Cbuf);
    conv1_mfma<<<3200, 256, 0, stream>>>(x, w1t, b1, hhi);
    prim_gemm_mfma<<<2304, 256, 0, stream>>>(hhi, wthi, Cbuf);
    squash_k<<<2304, 256, 0, stream>>>(Cbuf, pb, ut); // h region dead now
    priors_k<<<1440, 256, 0, stream>>>(ut, rw, pri);
    routing2_k<<<5120, 384, 0, stream>>>(pri, vbuf);
    dec1_k<<<512, 512, 0, stream>>>(vbuf, dw1, db1, out, d1);
    dec_gemm<0><<<128, 256, 0, stream>>>(d1, dw2, db2, d2, 512, 1024, 512);
    dec_gemm<1><<<104, 256, 0, stream>>>(d2, dw3, db3, out + 5120, 512, 784, 1024);
}

// Round 11
// 728.362 us; speedup vs baseline: 1.0933x; 1.0933x over previous
//
#include <hip/hip_runtime.h>
#include <math.h>

// ---------------------------------------------------------------------------
// CapsuleNet forward (round 28):
//  (1) conv1 epilogue REVERTED to round-26 direct h16x4 stores (r27's
//      LDS-staged epilogue regressed ~10us: 2 extra barriers + LDS RT cost
//      more than 32B->256B segments bought).
//  (2) prep_k float4 C-zeroing kept (r27, strictly fewer instructions).
//  (3) NEW: routing2 reduce-scatter butterfly: 17 shfl per 16-value wave
//      reduce (was 96) -> per-thread LDS-pipe ops 300 -> ~90. shfl ==
//      ds_swizzle == LDS pipe; routing2 est. ~60us of serialized LDS-pipe
//      at 120 waves/CU. Lane l<16 ends with full wave-sum of output l.
// Frozen: prim (297us floor, 7 mechanisms), conv1 staging/MFMA (r22/26),
// two-phase priors/routing (r6/12/14), dec1/dec_gemm (r12).
// ---------------------------------------------------------------------------

typedef _Float16 h16;
typedef h16 frag8 __attribute__((ext_vector_type(8)));    // 8 halves = 16 B
typedef h16 h16x4 __attribute__((ext_vector_type(4)));    // 4 halves = 8 B
typedef float f32x4 __attribute__((ext_vector_type(4)));

// workspace layout (BYTE offsets).
#define OFFB_HHI   0L             // 52428800 halves = 104857600 B
#define OFFB_WTHI  209715200L     // 5308416 halves = 10616832 B
#define OFFB_WT1   230948864L     // w1t: 24576 halves = 49152 B
#define OFFB_C     231031808L     // 4718592 floats -> end 249906176
#define WS_BYTES   249906176L
// aliased into dead h region after prim_gemm:
#define OFFB_PRI   0L             // 94371840 halves = 188743680 B (priors fp16)
#define OFFB_UT    188743680L     // 4718592 halves = 9437184 B -> OK
// aliased into dead wt region after prim_gemm:
#define OFFB_V     209715200L     // 81920 floats
#define OFFB_D1    210370560L     // 262144 floats
#define OFFB_D2    211419136L     // 524288 floats -> 213516288 OK

// async global->LDS, 16 B per lane. LDS dest must be lane-linear:
// lane i of a wave writes base + i*16 B.
#define GLL16(gp, lp)                                                        \
    __builtin_amdgcn_global_load_lds(                                        \
        (const __attribute__((address_space(1))) void*)(gp),                 \
        (__attribute__((address_space(3))) void*)(lp), 16, 0, 0)

// --------------------------------------------------------------------------
// wave reduce-scatter over 16 values: returns the FULL 64-lane sum of
// v[lane & 15]. 17 shfl (vs 96 for per-value butterfly). At xor-level b,
// keep the output whose bit b matches the lane bit, SEND the dropped one
// (partner symmetry: received value = partner's partial of the kept output).
__device__ __forceinline__ float wsr16(const float (&v)[16], int lane) {
    float t[8], u[4], w[2], z;
    int b0 = lane & 1, b1 = lane & 2, b2 = lane & 4, b3 = lane & 8;
#pragma unroll
    for (int j = 0; j < 8; ++j) {
        float k = b0 ? v[2 * j + 1] : v[2 * j];
        float s = b0 ? v[2 * j] : v[2 * j + 1];
        t[j] = k + __shfl_xor(s, 1);
    }
#pragma unroll
    for (int j = 0; j < 4; ++j) {
        float k = b1 ? t[2 * j + 1] : t[2 * j];
        float s = b1 ? t[2 * j] : t[2 * j + 1];
        u[j] = k + __shfl_xor(s, 2);
    }
#pragma unroll
    for (int j = 0; j < 2; ++j) {
        float k = b2 ? u[2 * j + 1] : u[2 * j];
        float s = b2 ? u[2 * j] : u[2 * j + 1];
        w[j] = k + __shfl_xor(s, 4);
    }
    {
        float k = b3 ? w[1] : w[0];
        float s = b3 ? w[0] : w[1];
        z = k + __shfl_xor(s, 8);
    }
    z += __shfl_xor(z, 16);
    z += __shfl_xor(z, 32);
    return z;
}

// --------------------------------------------------------------------------
// prep: blocks 0..95: w1t[oc][96] fp16 (k-padded); 96..351: prim B^T fp16;
// 352..1503: zero C via float4 (294912 float4/pass, 4 passes).
__global__ __launch_bounds__(256) void prep_k(const float* __restrict__ w1,
                                              const float* __restrict__ pw,
                                              h16* __restrict__ w1t,
                                              h16* __restrict__ whi,
                                              float* __restrict__ C) {
    __shared__ float s[2592];
    int bx = blockIdx.x, tid = threadIdx.x;
    if (bx < 96) {
        int k = bx, oc = tid;
        w1t[(long)oc * 96 + k] = (k < 81) ? (h16)w1[oc * 81 + k] : (h16)0.f;
    } else if (bx < 352) {
        int oc = bx - 96;
        long src0 = (long)oc * 20736, dst0 = src0;
        for (int ch = 0; ch < 8; ++ch) {
            int ic0 = ch * 32;
            __syncthreads();
            for (int e = tid; e < 2592; e += 256) s[e] = pw[src0 + ic0 * 81 + e];
            __syncthreads();
            for (int e = tid; e < 2592; e += 256) {
                int tap = e >> 5, icf = e & 31;
                whi[dst0 + tap * 256 + ic0 + icf] = (h16)s[icf * 81 + tap];
            }
        }
    } else {
        // 1152 blocks x 256 thr x 4 float4 = 4718592 floats exact
        float4* C4 = (float4*)C;
        long i = (long)(bx - 352) * 256 + tid;
        float4 z = make_float4(0.f, 0.f, 0.f, 0.f);
#pragma unroll
        for (int p = 0; p < 4; ++p) C4[i + (long)p * 294912] = z;
    }
}

// --------------------------------------------------------------------------
// conv1 as MFMA implicit-im2col GEMM. Grid 3200: nt = bx&1, mt = bx>>1.
// r22: pair-vectorized im2col + operand-swapped MFMA epilogue.
// r26: 3 blocks/CU + vectorized B-stage + setprio. (r27 epilogue reverted.)
#define CLDK 104
__global__ __launch_bounds__(256, 3) void conv1_mfma(const float* __restrict__ x,
                                                     const h16* __restrict__ w1t,
                                                     const float* __restrict__ bias,
                                                     h16* __restrict__ hhi) {
    __shared__ h16 Al[128 * CLDK];
    __shared__ h16 Bw[128 * CLDK];
    int tid = threadIdx.x;
    int bx = blockIdx.x;
    int nt = bx & 1, mt = bx >> 1;
    int n0 = nt * 128;

    // B stage: thread = (oc = tid>>1, half = tid&1) copies 48 contiguous
    // halves (96 B) as 6 x 16B vector ops. No division, coalesced.
    {
        int oc = tid >> 1, half = tid & 1;
        const frag8* src = (const frag8*)(w1t + (long)(n0 + oc) * 96 + half * 48);
        frag8* dst = (frag8*)(&Bw[oc * CLDK + half * 48]);
#pragma unroll
        for (int v = 0; v < 6; ++v) dst[v] = src[v];
    }
    // A stage: one (ml, ky) pair per step -> 9 contiguous x floats.
    for (int p = tid; p < 128 * 9; p += 256) {
        int ml = p / 9, ky = p - (p / 9) * 9;
        int m = mt * 128 + ml;
        int b = m / 400, pix = m - b * 400;
        int oy = pix / 20, ox = pix - oy * 20;
        const float* xs = x + (long)b * 784 + (oy + ky) * 28 + ox;
        h16* dst = &Al[ml * CLDK + ky * 9];
#pragma unroll
        for (int kx = 0; kx < 9; ++kx) dst[kx] = (h16)xs[kx];
    }
    // zero the k = 81..95 pad (MFMA reads through k=95).
    for (int e = tid; e < 128 * 16; e += 256) {
        int ml = e >> 4, kz = 81 + (e & 15);
        if (kz < 96) Al[ml * CLDK + kz] = (h16)0.f;
    }
    __syncthreads();

    int wave = tid >> 6;
    int wm = wave >> 1, wn = wave & 1;
    int lane = tid & 63;
    int lm = lane & 15, quad = lane >> 4;

    f32x4 acc[4][4];   // acc[ni][mi]: D rows = oc (quad*4+r), cols = m (lm)
#pragma unroll
    for (int i = 0; i < 4; ++i)
#pragma unroll
        for (int j = 0; j < 4; ++j) acc[i][j] = (f32x4){0.f, 0.f, 0.f, 0.f};

#pragma unroll
    for (int ks = 0; ks < 3; ++ks) {
        int kc = ks * 32 + quad * 8;
        frag8 af[4], bf[4];
#pragma unroll
        for (int mi = 0; mi < 4; ++mi)
            af[mi] = *(const frag8*)&Al[(wm * 64 + mi * 16 + lm) * CLDK + kc];
#pragma unroll
        for (int ni = 0; ni < 4; ++ni)
            bf[ni] = *(const frag8*)&Bw[(wn * 64 + ni * 16 + lm) * CLDK + kc];
        // operand swap: first operand's lm-space (oc) -> D rows (quad*4+r),
        // second operand's lm-space (m) -> D cols (lm).
        __builtin_amdgcn_s_setprio(1);
#pragma unroll
        for (int ni = 0; ni < 4; ++ni)
#pragma unroll
            for (int mi = 0; mi < 4; ++mi)
                acc[ni][mi] = __builtin_amdgcn_mfma_f32_16x16x32_f16(
                    bf[ni], af[mi], acc[ni][mi], 0, 0, 0);
        __builtin_amdgcn_s_setprio(0);
    }

    // epilogue: lane owns oc = ocb..ocb+3 at fixed m -> one 8B store per
    // (ni,mi). Lanes {lm fixed, quad 0..3} form 32B contiguous segments.
#pragma unroll
    for (int ni = 0; ni < 4; ++ni) {
        int ocb = n0 + wn * 64 + ni * 16 + quad * 4;
        float4 bv = *(const float4*)(bias + ocb);
#pragma unroll
        for (int mi = 0; mi < 4; ++mi) {
            int m = mt * 128 + wm * 64 + mi * 16 + lm;
            h16x4 o;
            o[0] = (h16)fmaxf(acc[ni][mi][0] + bv.x, 0.f);
            o[1] = (h16)fmaxf(acc[ni][mi][1] + bv.y, 0.f);
            o[2] = (h16)fmaxf(acc[ni][mi][2] + bv.z, 0.f);
            o[3] = (h16)fmaxf(acc[ni][mi][3] + bv.w, 0.f);
            *(h16x4*)(hhi + (long)m * 256 + ocb) = o;
        }
    }
}

// --------------------------------------------------------------------------
// prim conv MFMA GEMM (round-24 EXACT, 297 us floor): BM=128 BN=128 BK=32,
// split-K x8 (kt = bx&7 -> XCD-pinned B slice). global_load_lds dwordx4
// into double-buffered LINEAR LDS [128][32]; one barrier per K-step;
// setprio(1) around MFMA cluster. Atomic accumulate into zeroed C.
__global__ __launch_bounds__(256, 4) void prim_gemm_mfma(
        const h16* __restrict__ Ahi, const h16* __restrict__ Bhi,
        float* __restrict__ C) {
    __shared__ __align__(16) h16 As[2][128 * 32];
    __shared__ __align__(16) h16 Bs[2][128 * 32];
    int tid = threadIdx.x;
    int bx = blockIdx.x;                  // 2304 blocks
    int kt = bx & 7;
    int nt = (bx >> 3) & 1;
    int mt = bx >> 4;                     // 0..143
    int n0 = nt * 128;
    int kb0 = kt * 81;

    int wave = tid >> 6;
    int wm = wave >> 1, wn = wave & 1;
    int lane = tid & 63;
    int lm = lane & 15, quad = lane >> 4;

    // staging geometry: thread t, chunk q in {0,1} covers LDS halves
    // [t*8 + q*2048, +8)  ->  row r = (t>>2) + q*64, col c = (t&3)*8.
    int c0 = (tid & 3) * 8;
    int r0 = tid >> 2;
    long abase0, abase1, bbase0, bbase1;
    {
        int m = mt * 128 + r0;
        int b = m / 36, pos = m - b * 36;
        int oy = pos / 6, ox = pos - oy * 6;
        abase0 = ((long)(b * 20 + 2 * oy) * 20 + 2 * ox) * 256 + c0;
        m = mt * 128 + r0 + 64;
        b = m / 36; pos = m - b * 36;
        oy = pos / 6; ox = pos - oy * 6;
        abase1 = ((long)(b * 20 + 2 * oy) * 20 + 2 * ox) * 256 + c0;
        bbase0 = (long)(n0 + r0) * 20736 + c0;
        bbase1 = (long)(n0 + r0 + 64) * 20736 + c0;
    }
    h16* la = &As[0][tid * 8];
    h16* lb = &Bs[0][tid * 8];

    auto stage = [&](int buf, int kb) {
        // wave-uniform K-step decode (lands in SGPRs)
        int tap = kb >> 3;
        int ic0 = (kb & 7) << 5;
        int ky = tap / 9, kx = tap - ky * 9;
        long aoff = (long)(ky * 20 + kx) * 256 + ic0;
        long boff = (long)kb * 32;
        long lo = (long)buf * 4096;       // halves per buffer
        GLL16(Ahi + abase0 + aoff, la + lo);
        GLL16(Ahi + abase1 + aoff, la + lo + 2048);
        GLL16(Bhi + bbase0 + boff, lb + lo);
        GLL16(Bhi + bbase1 + boff, lb + lo + 2048);
    };

    f32x4 acc[4][4];
#pragma unroll
    for (int i = 0; i < 4; ++i)
#pragma unroll
        for (int j = 0; j < 4; ++j) acc[i][j] = (f32x4){0.f, 0.f, 0.f, 0.f};

    stage(0, kb0);
    for (int it = 0; it < 81; ++it) {
        int cur = it & 1;
        // one barrier per K-step: drains vmcnt (buf[cur] staged) and lgkm
        // (prev iter's ds_reads of buf[cur^1] done before we overwrite it).
        __syncthreads();
        if (it + 1 < 81) stage(cur ^ 1, kb0 + it + 1);

        frag8 ah[4], bh[4];
#pragma unroll
        for (int mi = 0; mi < 4; ++mi) {
            int row = wm * 64 + mi * 16 + lm;
            ah[mi] = *(const frag8*)&As[cur][row * 32 + quad * 8];
        }
#pragma unroll
        for (int ni = 0; ni < 4; ++ni) {
            int col = wn * 64 + ni * 16 + lm;
            bh[ni] = *(const frag8*)&Bs[cur][col * 32 + quad * 8];
        }
        __builtin_amdgcn_s_setprio(1);
#pragma unroll
        for (int mi = 0; mi < 4; ++mi)
#pragma unroll
            for (int ni = 0; ni < 4; ++ni)
                acc[mi][ni] = __builtin_amdgcn_mfma_f32_16x16x32_f16(
                    ah[mi], bh[ni], acc[mi][ni], 0, 0, 0);
        __builtin_amdgcn_s_setprio(0);
    }

#pragma unroll
    for (int ni = 0; ni < 4; ++ni) {
        int n = n0 + wn * 64 + ni * 16 + lm;
#pragma unroll
        for (int mi = 0; mi < 4; ++mi) {
            int m = mt * 128 + wm * 64 + mi * 16 + quad * 4;
#pragma unroll
            for (int r = 0; r < 4; ++r)
                atomicAdd(&C[(long)(m + r) * 256 + n], acc[mi][ni][r]);
        }
    }
}

// --------------------------------------------------------------------------
// squash: C[(b*36+pos)][256] (+bias) -> ut[n][b][8] fp16, n = ci*36+pos.
__global__ void squash_k(const float* __restrict__ C,
                         const float* __restrict__ bias,
                         h16* __restrict__ ut) {
    int t = blockIdx.x * 256 + threadIdx.x;          // 589824 exact
    int row = t >> 5;                                 // (b*36+pos)
    int ci = t & 31;
    int b = row / 36, pos = row - b * 36;
    const float* src = C + (long)row * 256 + ci;
    float v[8]; float sn = 0.f;
#pragma unroll
    for (int i = 0; i < 8; ++i) {
        v[i] = src[i * 32] + bias[ci + i * 32];
        sn = fmaf(v[i], v[i], sn);
    }
    float scale = (sn / (1.f + sn)) / sqrtf(sn);
    frag8 o;
#pragma unroll
    for (int i = 0; i < 8; ++i) o[i] = (h16)(v[i] * scale);
    *(frag8*)(ut + ((long)(ci * 36 + pos) * 512 + b) * 8) = o;
}

// --------------------------------------------------------------------------
// Phase A: priors[c,b,n,:16] = ut[n,b,:8] @ rw[c,n,:8,:16], fp16 out.
__global__ __launch_bounds__(256) void priors_k(const h16* __restrict__ ut,
                                                const float* __restrict__ rw,
                                                h16* __restrict__ priors) {
    int bid = blockIdx.x;                 // 1440 = 10 c * 144 n-groups
    int c = bid / 144, ng = bid - c * 144;
    int n0 = ng * 8;
    __shared__ float w[8][132];
    int tid = threadIdx.x;
    for (int e = tid; e < 1024; e += 256)
        w[e >> 7][e & 127] = rw[((long)c * 1152 + n0 + (e >> 7)) * 128 + (e & 127)];
    __syncthreads();
    int nl = tid & 7, bl = tid >> 3;      // bl 0..31
    int n = n0 + nl;
    for (int ch = 0; ch < 16; ++ch) {
        int b = ch * 32 + bl;
        frag8 uv = *(const frag8*)(ut + ((long)n * 512 + b) * 8);
        float uu[8];
#pragma unroll
        for (int i = 0; i < 8; ++i) uu[i] = (float)uv[i];
        float o[16];
#pragma unroll
        for (int j = 0; j < 16; ++j) o[j] = 0.f;
#pragma unroll
        for (int i = 0; i < 8; ++i)
#pragma unroll
            for (int j = 0; j < 16; ++j)
                o[j] = fmaf(uu[i], w[nl][i * 16 + j], o[j]);
        frag8 p0, p1;
#pragma unroll
        for (int j = 0; j < 8; ++j) { p0[j] = (h16)o[j]; p1[j] = (h16)o[j + 8]; }
        h16* dst = priors + ((long)(c * 512 + b) * 1152 + n) * 16;
        *(frag8*)dst = p0;
        *(frag8*)(dst + 8) = p1;
    }
}

// --------------------------------------------------------------------------
// Phase B: 3-iter routing. Block per (c,b). it0 = exact uniform-softmax
// shortcut. r28: reduce-scatter wave reduction (wsr16): 17 shfl per
// 16-value reduce (was 96); lane l<16 holds full sum of output l.
__global__ __launch_bounds__(384) void routing2_k(const h16* __restrict__ priors,
                                                  float* __restrict__ vbuf) {
    int c = blockIdx.x >> 9;
    int b = blockIdx.x & 511;
    int tid = threadIdx.x;
    int wid = tid >> 6;
    int lane = tid & 63;
    __shared__ float wred[6][20];

    float pr[3][16];
#pragma unroll
    for (int r = 0; r < 3; ++r) {
        int n = tid + r * 384;
        const h16* pp = priors + ((long)(c * 512 + b) * 1152 + n) * 16;
        frag8 p0 = *(const frag8*)pp;
        frag8 p1 = *(const frag8*)(pp + 8);
#pragma unroll
        for (int o = 0; o < 8; ++o) { pr[r][o] = (float)p0[o]; pr[r][o + 8] = (float)p1[o]; }
    }

    float l0 = 0.f, l1 = 0.f, l2 = 0.f;
    float vout[16];

    // ---- iteration 0: probs uniform = 1/1152 ----
    {
        float red[16];
#pragma unroll
        for (int o = 0; o < 16; ++o) red[o] = pr[0][o] + pr[1][o] + pr[2][o];
        float z = wsr16(red, lane);           // full sum of output (lane&15)
        if (lane < 16) wred[wid][lane] = z;
        __syncthreads();
        float inv = 1.f / 1152.f;
        float sn = 0.f;
        float sv[16];
#pragma unroll
        for (int o = 0; o < 16; ++o) {
            float tacc = wred[0][o];
#pragma unroll
            for (int w = 1; w < 6; ++w) tacc += wred[w][o];
            sv[o] = tacc * inv;
            sn = fmaf(sv[o], sv[o], sn);
        }
        float scale = (sn / (1.f + sn)) / sqrtf(sn);
#pragma unroll
        for (int o = 0; o < 16; ++o) vout[o] = sv[o] * scale;
        float d0 = 0.f, d1 = 0.f, d2 = 0.f;
#pragma unroll
        for (int o = 0; o < 16; ++o) {
            d0 = fmaf(pr[0][o], vout[o], d0);
            d1 = fmaf(pr[1][o], vout[o], d1);
            d2 = fmaf(pr[2][o], vout[o], d2);
        }
        l0 = d0; l1 = d1; l2 = d2;
        __syncthreads();                 // wred reused next iteration
    }

    // ---- iterations 1,2: full softmax path ----
    for (int it = 1; it < 3; ++it) {
        float lm = fmaxf(fmaxf(l0, l1), l2);
#pragma unroll
        for (int m = 32; m >= 1; m >>= 1) lm = fmaxf(lm, __shfl_xor(lm, m));
        if (lane == 0) wred[wid][17] = lm;
        __syncthreads();
        float maxv = wred[0][17];
#pragma unroll
        for (int w = 1; w < 6; ++w) maxv = fmaxf(maxv, wred[w][17]);

        float e0 = expf(l0 - maxv), e1 = expf(l1 - maxv), e2 = expf(l2 - maxv);
        float red[16];
#pragma unroll
        for (int o = 0; o < 16; ++o)
            red[o] = fmaf(e0, pr[0][o], fmaf(e1, pr[1][o], e2 * pr[2][o]));
        float red16 = e0 + e1 + e2;
        float z = wsr16(red, lane);           // full sum of output (lane&15)
#pragma unroll
        for (int m = 32; m >= 1; m >>= 1) red16 += __shfl_xor(red16, m);
        __syncthreads();
        if (lane < 16) wred[wid][lane] = z;
        if (lane == 16) wred[wid][16] = red16;
        __syncthreads();
        float sv[17];
#pragma unroll
        for (int o = 0; o < 17; ++o) {
            float tacc = wred[0][o];
#pragma unroll
            for (int w = 1; w < 6; ++w) tacc += wred[w][o];
            sv[o] = tacc;
        }
        float inv = 1.f / sv[16];
        float sn = 0.f;
#pragma unroll
        for (int o = 0; o < 16; ++o) { float s = sv[o] * inv; sn = fmaf(s, s, sn); }
        float scale = (sn / (1.f + sn)) / sqrtf(sn);
#pragma unroll
        for (int o = 0; o < 16; ++o) vout[o] = sv[o] * inv * scale;

        if (it < 2) {
            float d0 = 0.f, d1 = 0.f, d2 = 0.f;
#pragma unroll
            for (int o = 0; o < 16; ++o) {
                d0 = fmaf(pr[0][o], vout[o], d0);
                d1 = fmaf(pr[1][o], vout[o], d1);
                d2 = fmaf(pr[2][o], vout[o], d2);
            }
            l0 += d0; l1 += d1; l2 += d2;
        }
    }
    if (tid < 16) vbuf[(b * 10 + c) * 16 + tid] = vout[tid];
}

// --------------------------------------------------------------------------
// dec1: fused classes/argmax/y_pred + sparse masked GEMM (K=16 of 160).
__global__ __launch_bounds__(512) void dec1_k(const float* __restrict__ vbuf,
                                              const float* __restrict__ dw1,
                                              const float* __restrict__ db1,
                                              float* __restrict__ out,
                                              float* __restrict__ d1) {
    __shared__ float sv[160];
    __shared__ float scls[10];
    __shared__ int sbest;
    int b = blockIdx.x, tid = threadIdx.x;
    if (tid < 160) sv[tid] = vbuf[b * 160 + tid];
    __syncthreads();
    if (tid < 10) {
        float sn = 0.f;
#pragma unroll
        for (int o = 0; o < 16; ++o) { float v = sv[tid * 16 + o]; sn = fmaf(v, v, sn); }
        scls[tid] = sqrtf(sn);
    }
    __syncthreads();
    if (tid == 0) {
        int best = 0; float bv = scls[0];
#pragma unroll
        for (int cc = 1; cc < 10; ++cc) if (scls[cc] > bv) { bv = scls[cc]; best = cc; }
        sbest = best;
    }
    __syncthreads();
    int best = sbest;
    if (tid < 10) {
        out[b * 10 + tid] = (tid == best) ? 1.f : 0.f;          // y_pred
        out[406528 + b * 10 + tid] = scls[tid];                 // classes
    }
    float acc = db1[tid];
    const float* wrow = dw1 + (long)best * 16 * 512;
#pragma unroll
    for (int i = 0; i < 16; ++i)
        acc = fmaf(sv[best * 16 + i], wrow[i * 512 + tid], acc);
    d1[(long)b * 512 + tid] = fmaxf(acc, 0.f);
}

// --------------------------------------------------------------------------
template <int ACT>
__global__ __launch_bounds__(256) void dec_gemm(const float* __restrict__ A,
                                                const float* __restrict__ Bw,
                                                const float* __restrict__ bias,
                                                float* __restrict__ C,
                                                int M, int N, int K) {
    __shared__ float As[16][68];
    __shared__ float Bs[16][68];
    int ntiles = (N + 63) >> 6;
    int mt = blockIdx.x / ntiles, nt = blockIdx.x - mt * ntiles;
    int m0 = mt * 64, n0 = nt * 64;
    int tid = threadIdx.x;
    int tx = tid & 15, ty = tid >> 4;
    int am = tid >> 2, ak = (tid & 3) * 4;
    int bk = tid >> 4, bn = (tid & 15) * 4;
    float acc[4][4];
#pragma unroll
    for (int i = 0; i < 4; ++i)
#pragma unroll
        for (int j = 0; j < 4; ++j) acc[i][j] = 0.f;

    for (int k0 = 0; k0 < K; k0 += 16) {
        float4 av = *(const float4*)(A + (m0 + am) * K + k0 + ak);
        float4 bv = make_float4(0.f, 0.f, 0.f, 0.f);
        if (n0 + bn < N) bv = *(const float4*)(Bw + (k0 + bk) * N + n0 + bn);
        __syncthreads();
        As[ak + 0][am] = av.x;
        As[ak + 1][am] = av.y;
        As[ak + 2][am] = av.z;
        As[ak + 3][am] = av.w;
        *(float4*)&Bs[bk][bn] = bv;
        __syncthreads();
#pragma unroll
        for (int kk = 0; kk < 16; ++kk) {
            float4 a = *(const float4*)&As[kk][ty * 4];
            float4 bb = *(const float4*)&Bs[kk][tx * 4];
            float aa[4] = {a.x, a.y, a.z, a.w};
            float bbb[4] = {bb.x, bb.y, bb.z, bb.w};
#pragma unroll
            for (int i = 0; i < 4; ++i)
#pragma unroll
                for (int j = 0; j < 4; ++j)
                    acc[i][j] = fmaf(aa[i], bbb[j], acc[i][j]);
        }
    }
#pragma unroll
    for (int i = 0; i < 4; ++i) {
        int m = m0 + ty * 4 + i;
#pragma unroll
        for (int j = 0; j < 4; ++j) {
            int n = n0 + tx * 4 + j;
            if (n < N) {
                float v = acc[i][j] + bias[n];
                if (ACT == 0) v = fmaxf(v, 0.f);
                else          v = 1.f / (1.f + expf(-v));
                C[m * N + n] = v;
            }
        }
    }
}

// --------------------------------------------------------------------------
extern "C" void kernel_launch(void* const* d_in, const int* in_sizes, int n_in,
                              void* d_out, int out_size, void* d_ws, size_t ws_size,
                              hipStream_t stream) {
    const float* x   = (const float*)d_in[0];
    const float* w1  = (const float*)d_in[1];
    const float* b1  = (const float*)d_in[2];
    const float* pw  = (const float*)d_in[3];
    const float* pb  = (const float*)d_in[4];
    const float* rw  = (const float*)d_in[5];
    const float* dw1 = (const float*)d_in[6];
    const float* db1 = (const float*)d_in[7];
    const float* dw2 = (const float*)d_in[8];
    const float* db2 = (const float*)d_in[9];
    const float* dw3 = (const float*)d_in[10];
    const float* db3 = (const float*)d_in[11];
    float* out = (float*)d_out;
    char* wsb  = (char*)d_ws;
    if (ws_size < (size_t)WS_BYTES) return;

    h16*   hhi  = (h16*)(wsb + OFFB_HHI);
    h16*   wthi = (h16*)(wsb + OFFB_WTHI);
    h16*   w1t  = (h16*)(wsb + OFFB_WT1);
    float* Cbuf = (float*)(wsb + OFFB_C);
    h16*   pri  = (h16*)(wsb + OFFB_PRI);
    h16*   ut   = (h16*)(wsb + OFFB_UT);
    float* vbuf = (float*)(wsb + OFFB_V);
    float* d1   = (float*)(wsb + OFFB_D1);
    float* d2   = (float*)(wsb + OFFB_D2);

    prep_k<<<1504, 256, 0, stream>>>(w1, pw, w1t, wthi, Cbuf);
    conv1_mfma<<<3200, 256, 0, stream>>>(x, w1t, b1, hhi);
    prim_gemm_mfma<<<2304, 256, 0, stream>>>(hhi, wthi, Cbuf);
    squash_k<<<2304, 256, 0, stream>>>(Cbuf, pb, ut); // h region dead now
    priors_k<<<1440, 256, 0, stream>>>(ut, rw, pri);
    routing2_k<<<5120, 384, 0, stream>>>(pri, vbuf);
    dec1_k<<<512, 512, 0, stream>>>(vbuf, dw1, db1, out, d1);
    dec_gemm<0><<<128, 256, 0, stream>>>(d1, dw2, db2, d2, 512, 1024, 512);
    dec_gemm<1><<<104, 256, 0, stream>>>(d2, dw3, db3, out + 5120, 512, 784, 1024);
}

// Round 12
// 692.885 us; speedup vs baseline: 1.1493x; 1.0512x over previous
//
#include <hip/hip_runtime.h>
#include <math.h>

// ---------------------------------------------------------------------------
// CapsuleNet forward (round 29): routing2 cross-wave combine delegated.
// r28 insight confirmed (+68us): shfl = LDS-pipe op; routing2 is LDS-pipe
// bound. Remaining term: EVERY thread re-summed wred[0..5][o] for 16-17
// outputs = ~300 ds_read_b32/thread over 3 iters (more than the shuffles
// r28 removed). Now: stage-2 on threads 0..16 only (6 reads + 1 shfl bcast
// + 4 shfl square-reduce), vout broadcast via 4x ds_read_b128; it2 writes
// vbuf directly. ~390 -> ~100 LDS-pipe ops/thread.
// Frozen: prim (297-303us floor, 7 mechanisms tried), conv1 (r22/26),
// prep float4-zero (r27), wsr16 (r28), two-phase, dec1/dec_gemm.
// ---------------------------------------------------------------------------

typedef _Float16 h16;
typedef h16 frag8 __attribute__((ext_vector_type(8)));    // 8 halves = 16 B
typedef h16 h16x4 __attribute__((ext_vector_type(4)));    // 4 halves = 8 B
typedef float f32x4 __attribute__((ext_vector_type(4)));

// workspace layout (BYTE offsets).
#define OFFB_HHI   0L             // 52428800 halves = 104857600 B
#define OFFB_WTHI  209715200L     // 5308416 halves = 10616832 B
#define OFFB_WT1   230948864L     // w1t: 24576 halves = 49152 B
#define OFFB_C     231031808L     // 4718592 floats -> end 249906176
#define WS_BYTES   249906176L
// aliased into dead h region after prim_gemm:
#define OFFB_PRI   0L             // 94371840 halves = 188743680 B (priors fp16)
#define OFFB_UT    188743680L     // 4718592 halves = 9437184 B -> OK
// aliased into dead wt region after prim_gemm:
#define OFFB_V     209715200L     // 81920 floats
#define OFFB_D1    210370560L     // 262144 floats
#define OFFB_D2    211419136L     // 524288 floats -> 213516288 OK

// async global->LDS, 16 B per lane. LDS dest must be lane-linear:
// lane i of a wave writes base + i*16 B.
#define GLL16(gp, lp)                                                        \
    __builtin_amdgcn_global_load_lds(                                        \
        (const __attribute__((address_space(1))) void*)(gp),                 \
        (__attribute__((address_space(3))) void*)(lp), 16, 0, 0)

// --------------------------------------------------------------------------
// wave reduce-scatter over 16 values: returns the FULL 64-lane sum of
// v[lane & 15]. 17 shfl (vs 96 for per-value butterfly). At xor-level b,
// keep the output whose bit b matches the lane bit, SEND the dropped one
// (partner symmetry: received value = partner's partial of the kept output).
__device__ __forceinline__ float wsr16(const float (&v)[16], int lane) {
    float t[8], u[4], w[2], z;
    int b0 = lane & 1, b1 = lane & 2, b2 = lane & 4, b3 = lane & 8;
#pragma unroll
    for (int j = 0; j < 8; ++j) {
        float k = b0 ? v[2 * j + 1] : v[2 * j];
        float s = b0 ? v[2 * j] : v[2 * j + 1];
        t[j] = k + __shfl_xor(s, 1);
    }
#pragma unroll
    for (int j = 0; j < 4; ++j) {
        float k = b1 ? t[2 * j + 1] : t[2 * j];
        float s = b1 ? t[2 * j] : t[2 * j + 1];
        u[j] = k + __shfl_xor(s, 2);
    }
#pragma unroll
    for (int j = 0; j < 2; ++j) {
        float k = b2 ? u[2 * j + 1] : u[2 * j];
        float s = b2 ? u[2 * j] : u[2 * j + 1];
        w[j] = k + __shfl_xor(s, 4);
    }
    {
        float k = b3 ? w[1] : w[0];
        float s = b3 ? w[0] : w[1];
        z = k + __shfl_xor(s, 8);
    }
    z += __shfl_xor(z, 16);
    z += __shfl_xor(z, 32);
    return z;
}

// --------------------------------------------------------------------------
// prep: blocks 0..95: w1t[oc][96] fp16 (k-padded); 96..351: prim B^T fp16;
// 352..1503: zero C via float4 (294912 float4/pass, 4 passes).
__global__ __launch_bounds__(256) void prep_k(const float* __restrict__ w1,
                                              const float* __restrict__ pw,
                                              h16* __restrict__ w1t,
                                              h16* __restrict__ whi,
                                              float* __restrict__ C) {
    __shared__ float s[2592];
    int bx = blockIdx.x, tid = threadIdx.x;
    if (bx < 96) {
        int k = bx, oc = tid;
        w1t[(long)oc * 96 + k] = (k < 81) ? (h16)w1[oc * 81 + k] : (h16)0.f;
    } else if (bx < 352) {
        int oc = bx - 96;
        long src0 = (long)oc * 20736, dst0 = src0;
        for (int ch = 0; ch < 8; ++ch) {
            int ic0 = ch * 32;
            __syncthreads();
            for (int e = tid; e < 2592; e += 256) s[e] = pw[src0 + ic0 * 81 + e];
            __syncthreads();
            for (int e = tid; e < 2592; e += 256) {
                int tap = e >> 5, icf = e & 31;
                whi[dst0 + tap * 256 + ic0 + icf] = (h16)s[icf * 81 + tap];
            }
        }
    } else {
        // 1152 blocks x 256 thr x 4 float4 = 4718592 floats exact
        float4* C4 = (float4*)C;
        long i = (long)(bx - 352) * 256 + tid;
        float4 z = make_float4(0.f, 0.f, 0.f, 0.f);
#pragma unroll
        for (int p = 0; p < 4; ++p) C4[i + (long)p * 294912] = z;
    }
}

// --------------------------------------------------------------------------
// conv1 as MFMA implicit-im2col GEMM. Grid 3200: nt = bx&1, mt = bx>>1.
// r22: pair-vectorized im2col + operand-swapped MFMA epilogue.
// r26: 3 blocks/CU + vectorized B-stage + setprio.
#define CLDK 104
__global__ __launch_bounds__(256, 3) void conv1_mfma(const float* __restrict__ x,
                                                     const h16* __restrict__ w1t,
                                                     const float* __restrict__ bias,
                                                     h16* __restrict__ hhi) {
    __shared__ h16 Al[128 * CLDK];
    __shared__ h16 Bw[128 * CLDK];
    int tid = threadIdx.x;
    int bx = blockIdx.x;
    int nt = bx & 1, mt = bx >> 1;
    int n0 = nt * 128;

    // B stage: thread = (oc = tid>>1, half = tid&1) copies 48 contiguous
    // halves (96 B) as 6 x 16B vector ops. No division, coalesced.
    {
        int oc = tid >> 1, half = tid & 1;
        const frag8* src = (const frag8*)(w1t + (long)(n0 + oc) * 96 + half * 48);
        frag8* dst = (frag8*)(&Bw[oc * CLDK + half * 48]);
#pragma unroll
        for (int v = 0; v < 6; ++v) dst[v] = src[v];
    }
    // A stage: one (ml, ky) pair per step -> 9 contiguous x floats.
    for (int p = tid; p < 128 * 9; p += 256) {
        int ml = p / 9, ky = p - (p / 9) * 9;
        int m = mt * 128 + ml;
        int b = m / 400, pix = m - b * 400;
        int oy = pix / 20, ox = pix - oy * 20;
        const float* xs = x + (long)b * 784 + (oy + ky) * 28 + ox;
        h16* dst = &Al[ml * CLDK + ky * 9];
#pragma unroll
        for (int kx = 0; kx < 9; ++kx) dst[kx] = (h16)xs[kx];
    }
    // zero the k = 81..95 pad (MFMA reads through k=95).
    for (int e = tid; e < 128 * 16; e += 256) {
        int ml = e >> 4, kz = 81 + (e & 15);
        if (kz < 96) Al[ml * CLDK + kz] = (h16)0.f;
    }
    __syncthreads();

    int wave = tid >> 6;
    int wm = wave >> 1, wn = wave & 1;
    int lane = tid & 63;
    int lm = lane & 15, quad = lane >> 4;

    f32x4 acc[4][4];   // acc[ni][mi]: D rows = oc (quad*4+r), cols = m (lm)
#pragma unroll
    for (int i = 0; i < 4; ++i)
#pragma unroll
        for (int j = 0; j < 4; ++j) acc[i][j] = (f32x4){0.f, 0.f, 0.f, 0.f};

#pragma unroll
    for (int ks = 0; ks < 3; ++ks) {
        int kc = ks * 32 + quad * 8;
        frag8 af[4], bf[4];
#pragma unroll
        for (int mi = 0; mi < 4; ++mi)
            af[mi] = *(const frag8*)&Al[(wm * 64 + mi * 16 + lm) * CLDK + kc];
#pragma unroll
        for (int ni = 0; ni < 4; ++ni)
            bf[ni] = *(const frag8*)&Bw[(wn * 64 + ni * 16 + lm) * CLDK + kc];
        // operand swap: first operand's lm-space (oc) -> D rows (quad*4+r),
        // second operand's lm-space (m) -> D cols (lm).
        __builtin_amdgcn_s_setprio(1);
#pragma unroll
        for (int ni = 0; ni < 4; ++ni)
#pragma unroll
            for (int mi = 0; mi < 4; ++mi)
                acc[ni][mi] = __builtin_amdgcn_mfma_f32_16x16x32_f16(
                    bf[ni], af[mi], acc[ni][mi], 0, 0, 0);
        __builtin_amdgcn_s_setprio(0);
    }

    // epilogue: lane owns oc = ocb..ocb+3 at fixed m -> one 8B store per
    // (ni,mi). Lanes {lm fixed, quad 0..3} form 32B contiguous segments.
#pragma unroll
    for (int ni = 0; ni < 4; ++ni) {
        int ocb = n0 + wn * 64 + ni * 16 + quad * 4;
        float4 bv = *(const float4*)(bias + ocb);
#pragma unroll
        for (int mi = 0; mi < 4; ++mi) {
            int m = mt * 128 + wm * 64 + mi * 16 + lm;
            h16x4 o;
            o[0] = (h16)fmaxf(acc[ni][mi][0] + bv.x, 0.f);
            o[1] = (h16)fmaxf(acc[ni][mi][1] + bv.y, 0.f);
            o[2] = (h16)fmaxf(acc[ni][mi][2] + bv.z, 0.f);
            o[3] = (h16)fmaxf(acc[ni][mi][3] + bv.w, 0.f);
            *(h16x4*)(hhi + (long)m * 256 + ocb) = o;
        }
    }
}

// --------------------------------------------------------------------------
// prim conv MFMA GEMM (round-24 EXACT, 297 us floor): BM=128 BN=128 BK=32,
// split-K x8 (kt = bx&7 -> XCD-pinned B slice). global_load_lds dwordx4
// into double-buffered LINEAR LDS [128][32]; one barrier per K-step;
// setprio(1) around MFMA cluster. Atomic accumulate into zeroed C.
__global__ __launch_bounds__(256, 4) void prim_gemm_mfma(
        const h16* __restrict__ Ahi, const h16* __restrict__ Bhi,
        float* __restrict__ C) {
    __shared__ __align__(16) h16 As[2][128 * 32];
    __shared__ __align__(16) h16 Bs[2][128 * 32];
    int tid = threadIdx.x;
    int bx = blockIdx.x;                  // 2304 blocks
    int kt = bx & 7;
    int nt = (bx >> 3) & 1;
    int mt = bx >> 4;                     // 0..143
    int n0 = nt * 128;
    int kb0 = kt * 81;

    int wave = tid >> 6;
    int wm = wave >> 1, wn = wave & 1;
    int lane = tid & 63;
    int lm = lane & 15, quad = lane >> 4;

    // staging geometry: thread t, chunk q in {0,1} covers LDS halves
    // [t*8 + q*2048, +8)  ->  row r = (t>>2) + q*64, col c = (t&3)*8.
    int c0 = (tid & 3) * 8;
    int r0 = tid >> 2;
    long abase0, abase1, bbase0, bbase1;
    {
        int m = mt * 128 + r0;
        int b = m / 36, pos = m - b * 36;
        int oy = pos / 6, ox = pos - oy * 6;
        abase0 = ((long)(b * 20 + 2 * oy) * 20 + 2 * ox) * 256 + c0;
        m = mt * 128 + r0 + 64;
        b = m / 36; pos = m - b * 36;
        oy = pos / 6; ox = pos - oy * 6;
        abase1 = ((long)(b * 20 + 2 * oy) * 20 + 2 * ox) * 256 + c0;
        bbase0 = (long)(n0 + r0) * 20736 + c0;
        bbase1 = (long)(n0 + r0 + 64) * 20736 + c0;
    }
    h16* la = &As[0][tid * 8];
    h16* lb = &Bs[0][tid * 8];

    auto stage = [&](int buf, int kb) {
        // wave-uniform K-step decode (lands in SGPRs)
        int tap = kb >> 3;
        int ic0 = (kb & 7) << 5;
        int ky = tap / 9, kx = tap - ky * 9;
        long aoff = (long)(ky * 20 + kx) * 256 + ic0;
        long boff = (long)kb * 32;
        long lo = (long)buf * 4096;       // halves per buffer
        GLL16(Ahi + abase0 + aoff, la + lo);
        GLL16(Ahi + abase1 + aoff, la + lo + 2048);
        GLL16(Bhi + bbase0 + boff, lb + lo);
        GLL16(Bhi + bbase1 + boff, lb + lo + 2048);
    };

    f32x4 acc[4][4];
#pragma unroll
    for (int i = 0; i < 4; ++i)
#pragma unroll
        for (int j = 0; j < 4; ++j) acc[i][j] = (f32x4){0.f, 0.f, 0.f, 0.f};

    stage(0, kb0);
    for (int it = 0; it < 81; ++it) {
        int cur = it & 1;
        // one barrier per K-step: drains vmcnt (buf[cur] staged) and lgkm
        // (prev iter's ds_reads of buf[cur^1] done before we overwrite it).
        __syncthreads();
        if (it + 1 < 81) stage(cur ^ 1, kb0 + it + 1);

        frag8 ah[4], bh[4];
#pragma unroll
        for (int mi = 0; mi < 4; ++mi) {
            int row = wm * 64 + mi * 16 + lm;
            ah[mi] = *(const frag8*)&As[cur][row * 32 + quad * 8];
        }
#pragma unroll
        for (int ni = 0; ni < 4; ++ni) {
            int col = wn * 64 + ni * 16 + lm;
            bh[ni] = *(const frag8*)&Bs[cur][col * 32 + quad * 8];
        }
        __builtin_amdgcn_s_setprio(1);
#pragma unroll
        for (int mi = 0; mi < 4; ++mi)
#pragma unroll
            for (int ni = 0; ni < 4; ++ni)
                acc[mi][ni] = __builtin_amdgcn_mfma_f32_16x16x32_f16(
                    ah[mi], bh[ni], acc[mi][ni], 0, 0, 0);
        __builtin_amdgcn_s_setprio(0);
    }

#pragma unroll
    for (int ni = 0; ni < 4; ++ni) {
        int n = n0 + wn * 64 + ni * 16 + lm;
#pragma unroll
        for (int mi = 0; mi < 4; ++mi) {
            int m = mt * 128 + wm * 64 + mi * 16 + quad * 4;
#pragma unroll
            for (int r = 0; r < 4; ++r)
                atomicAdd(&C[(long)(m + r) * 256 + n], acc[mi][ni][r]);
        }
    }
}

// --------------------------------------------------------------------------
// squash: C[(b*36+pos)][256] (+bias) -> ut[n][b][8] fp16, n = ci*36+pos.
__global__ void squash_k(const float* __restrict__ C,
                         const float* __restrict__ bias,
                         h16* __restrict__ ut) {
    int t = blockIdx.x * 256 + threadIdx.x;          // 589824 exact
    int row = t >> 5;                                 // (b*36+pos)
    int ci = t & 31;
    int b = row / 36, pos = row - b * 36;
    const float* src = C + (long)row * 256 + ci;
    float v[8]; float sn = 0.f;
#pragma unroll
    for (int i = 0; i < 8; ++i) {
        v[i] = src[i * 32] + bias[ci + i * 32];
        sn = fmaf(v[i], v[i], sn);
    }
    float scale = (sn / (1.f + sn)) / sqrtf(sn);
    frag8 o;
#pragma unroll
    for (int i = 0; i < 8; ++i) o[i] = (h16)(v[i] * scale);
    *(frag8*)(ut + ((long)(ci * 36 + pos) * 512 + b) * 8) = o;
}

// --------------------------------------------------------------------------
// Phase A: priors[c,b,n,:16] = ut[n,b,:8] @ rw[c,n,:8,:16], fp16 out.
__global__ __launch_bounds__(256) void priors_k(const h16* __restrict__ ut,
                                                const float* __restrict__ rw,
                                                h16* __restrict__ priors) {
    int bid = blockIdx.x;                 // 1440 = 10 c * 144 n-groups
    int c = bid / 144, ng = bid - c * 144;
    int n0 = ng * 8;
    __shared__ float w[8][132];
    int tid = threadIdx.x;
    for (int e = tid; e < 1024; e += 256)
        w[e >> 7][e & 127] = rw[((long)c * 1152 + n0 + (e >> 7)) * 128 + (e & 127)];
    __syncthreads();
    int nl = tid & 7, bl = tid >> 3;      // bl 0..31
    int n = n0 + nl;
    for (int ch = 0; ch < 16; ++ch) {
        int b = ch * 32 + bl;
        frag8 uv = *(const frag8*)(ut + ((long)n * 512 + b) * 8);
        float uu[8];
#pragma unroll
        for (int i = 0; i < 8; ++i) uu[i] = (float)uv[i];
        float o[16];
#pragma unroll
        for (int j = 0; j < 16; ++j) o[j] = 0.f;
#pragma unroll
        for (int i = 0; i < 8; ++i)
#pragma unroll
            for (int j = 0; j < 16; ++j)
                o[j] = fmaf(uu[i], w[nl][i * 16 + j], o[j]);
        frag8 p0, p1;
#pragma unroll
        for (int j = 0; j < 8; ++j) { p0[j] = (h16)o[j]; p1[j] = (h16)o[j + 8]; }
        h16* dst = priors + ((long)(c * 512 + b) * 1152 + n) * 16;
        *(frag8*)dst = p0;
        *(frag8*)(dst + 8) = p1;
    }
}

// --------------------------------------------------------------------------
// Phase B: 3-iter routing. Block per (c,b). it0 = exact uniform-softmax
// shortcut. r28: wsr16 reduce-scatter (17 shfl / 16-value reduce).
// r29: cross-wave combine delegated to threads 0..16; vout broadcast via
// 4x ds_read_b128 (was ~100 scalar ds_read per thread per iteration).
__global__ __launch_bounds__(384) void routing2_k(const h16* __restrict__ priors,
                                                  float* __restrict__ vbuf) {
    int c = blockIdx.x >> 9;
    int b = blockIdx.x & 511;
    int tid = threadIdx.x;
    int wid = tid >> 6;
    int lane = tid & 63;
    __shared__ float wred[6][20];
    __shared__ float wmax[6];
    __shared__ __align__(16) float vsh[16];

    float pr[3][16];
#pragma unroll
    for (int r = 0; r < 3; ++r) {
        int n = tid + r * 384;
        const h16* pp = priors + ((long)(c * 512 + b) * 1152 + n) * 16;
        frag8 p0 = *(const frag8*)pp;
        frag8 p1 = *(const frag8*)(pp + 8);
#pragma unroll
        for (int o = 0; o < 8; ++o) { pr[r][o] = (float)p0[o]; pr[r][o + 8] = (float)p1[o]; }
    }

    float l0 = 0.f, l1 = 0.f, l2 = 0.f;
    float vout[16];

    // ---- iteration 0: probs uniform = 1/1152 ----
    {
        float red[16];
#pragma unroll
        for (int o = 0; o < 16; ++o) red[o] = pr[0][o] + pr[1][o] + pr[2][o];
        float z = wsr16(red, lane);           // full sum of output (lane&15)
        if (lane < 16) wred[wid][lane] = z;
        __syncthreads();
        if (tid < 16) {
            float s = wred[0][tid];
#pragma unroll
            for (int w = 1; w < 6; ++w) s += wred[w][tid];
            s *= (1.f / 1152.f);
            float sn = s * s;
            sn += __shfl_xor(sn, 1);
            sn += __shfl_xor(sn, 2);
            sn += __shfl_xor(sn, 4);
            sn += __shfl_xor(sn, 8);
            float scale = (sn / (1.f + sn)) / sqrtf(sn);
            vsh[tid] = s * scale;
        }
        __syncthreads();
        {
            const float4* vv = (const float4*)vsh;
            float4 a0 = vv[0], a1 = vv[1], a2 = vv[2], a3 = vv[3];
            vout[0]=a0.x; vout[1]=a0.y; vout[2]=a0.z; vout[3]=a0.w;
            vout[4]=a1.x; vout[5]=a1.y; vout[6]=a1.z; vout[7]=a1.w;
            vout[8]=a2.x; vout[9]=a2.y; vout[10]=a2.z; vout[11]=a2.w;
            vout[12]=a3.x; vout[13]=a3.y; vout[14]=a3.z; vout[15]=a3.w;
        }
        float d0 = 0.f, d1 = 0.f, d2 = 0.f;
#pragma unroll
        for (int o = 0; o < 16; ++o) {
            d0 = fmaf(pr[0][o], vout[o], d0);
            d1 = fmaf(pr[1][o], vout[o], d1);
            d2 = fmaf(pr[2][o], vout[o], d2);
        }
        l0 = d0; l1 = d1; l2 = d2;
    }

    // ---- iteration 1 (full softmax; updates l) ----
    {
        float lm = fmaxf(fmaxf(l0, l1), l2);
#pragma unroll
        for (int m = 32; m >= 1; m >>= 1) lm = fmaxf(lm, __shfl_xor(lm, m));
        if (lane == 0) wmax[wid] = lm;
        __syncthreads();                 // also retires it0's vsh reads
        float maxv = wmax[0];
#pragma unroll
        for (int w = 1; w < 6; ++w) maxv = fmaxf(maxv, wmax[w]);

        float e0 = expf(l0 - maxv), e1 = expf(l1 - maxv), e2 = expf(l2 - maxv);
        float red[16];
#pragma unroll
        for (int o = 0; o < 16; ++o)
            red[o] = fmaf(e0, pr[0][o], fmaf(e1, pr[1][o], e2 * pr[2][o]));
        float red16 = e0 + e1 + e2;
        float z = wsr16(red, lane);
#pragma unroll
        for (int m = 32; m >= 1; m >>= 1) red16 += __shfl_xor(red16, m);
        if (lane < 16) wred[wid][lane] = z;
        else if (lane == 16) wred[wid][16] = red16;
        __syncthreads();
        if (tid < 17) {
            float s = wred[0][tid];
#pragma unroll
            for (int w = 1; w < 6; ++w) s += wred[w][tid];
            float den = __shfl(s, 16);
            float inv = 1.f / den;
            float t = s * inv;
            float sn = t * t;
            sn += __shfl_xor(sn, 1);
            sn += __shfl_xor(sn, 2);
            sn += __shfl_xor(sn, 4);
            sn += __shfl_xor(sn, 8);
            float scale = (sn / (1.f + sn)) / sqrtf(sn);
            if (tid < 16) vsh[tid] = t * scale;
        }
        __syncthreads();
        {
            const float4* vv = (const float4*)vsh;
            float4 a0 = vv[0], a1 = vv[1], a2 = vv[2], a3 = vv[3];
            vout[0]=a0.x; vout[1]=a0.y; vout[2]=a0.z; vout[3]=a0.w;
            vout[4]=a1.x; vout[5]=a1.y; vout[6]=a1.z; vout[7]=a1.w;
            vout[8]=a2.x; vout[9]=a2.y; vout[10]=a2.z; vout[11]=a2.w;
            vout[12]=a3.x; vout[13]=a3.y; vout[14]=a3.z; vout[15]=a3.w;
        }
        float d0 = 0.f, d1 = 0.f, d2 = 0.f;
#pragma unroll
        for (int o = 0; o < 16; ++o) {
            d0 = fmaf(pr[0][o], vout[o], d0);
            d1 = fmaf(pr[1][o], vout[o], d1);
            d2 = fmaf(pr[2][o], vout[o], d2);
        }
        l0 += d0; l1 += d1; l2 += d2;
    }

    // ---- iteration 2 (final; vbuf written directly from stage 2) ----
    {
        float lm = fmaxf(fmaxf(l0, l1), l2);
#pragma unroll
        for (int m = 32; m >= 1; m >>= 1) lm = fmaxf(lm, __shfl_xor(lm, m));
        if (lane == 0) wmax[wid] = lm;
        __syncthreads();                 // retires it1's vsh reads
        float maxv = wmax[0];
#pragma unroll
        for (int w = 1; w < 6; ++w) maxv = fmaxf(maxv, wmax[w]);

        float e0 = expf(l0 - maxv), e1 = expf(l1 - maxv), e2 = expf(l2 - maxv);
        float red[16];
#pragma unroll
        for (int o = 0; o < 16; ++o)
            red[o] = fmaf(e0, pr[0][o], fmaf(e1, pr[1][o], e2 * pr[2][o]));
        float red16 = e0 + e1 + e2;
        float z = wsr16(red, lane);
#pragma unroll
        for (int m = 32; m >= 1; m >>= 1) red16 += __shfl_xor(red16, m);
        if (lane < 16) wred[wid][lane] = z;
        else if (lane == 16) wred[wid][16] = red16;
        __syncthreads();
        if (tid < 17) {
            float s = wred[0][tid];
#pragma unroll
            for (int w = 1; w < 6; ++w) s += wred[w][tid];
            float den = __shfl(s, 16);
            float inv = 1.f / den;
            float t = s * inv;
            float sn = t * t;
            sn += __shfl_xor(sn, 1);
            sn += __shfl_xor(sn, 2);
            sn += __shfl_xor(sn, 4);
            sn += __shfl_xor(sn, 8);
            float scale = (sn / (1.f + sn)) / sqrtf(sn);
            if (tid < 16) vbuf[(b * 10 + c) * 16 + tid] = t * scale;
        }
    }
}

// --------------------------------------------------------------------------
// dec1: fused classes/argmax/y_pred + sparse masked GEMM (K=16 of 160).
__global__ __launch_bounds__(512) void dec1_k(const float* __restrict__ vbuf,
                                              const float* __restrict__ dw1,
                                              const float* __restrict__ db1,
                                              float* __restrict__ out,
                                              float* __restrict__ d1) {
    __shared__ float sv[160];
    __shared__ float scls[10];
    __shared__ int sbest;
    int b = blockIdx.x, tid = threadIdx.x;
    if (tid < 160) sv[tid] = vbuf[b * 160 + tid];
    __syncthreads();
    if (tid < 10) {
        float sn = 0.f;
#pragma unroll
        for (int o = 0; o < 16; ++o) { float v = sv[tid * 16 + o]; sn = fmaf(v, v, sn); }
        scls[tid] = sqrtf(sn);
    }
    __syncthreads();
    if (tid == 0) {
        int best = 0; float bv = scls[0];
#pragma unroll
        for (int cc = 1; cc < 10; ++cc) if (scls[cc] > bv) { bv = scls[cc]; best = cc; }
        sbest = best;
    }
    __syncthreads();
    int best = sbest;
    if (tid < 10) {
        out[b * 10 + tid] = (tid == best) ? 1.f : 0.f;          // y_pred
        out[406528 + b * 10 + tid] = scls[tid];                 // classes
    }
    float acc = db1[tid];
    const float* wrow = dw1 + (long)best * 16 * 512;
#pragma unroll
    for (int i = 0; i < 16; ++i)
        acc = fmaf(sv[best * 16 + i], wrow[i * 512 + tid], acc);
    d1[(long)b * 512 + tid] = fmaxf(acc, 0.f);
}

// --------------------------------------------------------------------------
template <int ACT>
__global__ __launch_bounds__(256) void dec_gemm(const float* __restrict__ A,
                                                const float* __restrict__ Bw,
                                                const float* __restrict__ bias,
                                                float* __restrict__ C,
                                                int M, int N, int K) {
    __shared__ float As[16][68];
    __shared__ float Bs[16][68];
    int ntiles = (N + 63) >> 6;
    int mt = blockIdx.x / ntiles, nt = blockIdx.x - mt * ntiles;
    int m0 = mt * 64, n0 = nt * 64;
    int tid = threadIdx.x;
    int tx = tid & 15, ty = tid >> 4;
    int am = tid >> 2, ak = (tid & 3) * 4;
    int bk = tid >> 4, bn = (tid & 15) * 4;
    float acc[4][4];
#pragma unroll
    for (int i = 0; i < 4; ++i)
#pragma unroll
        for (int j = 0; j < 4; ++j) acc[i][j] = 0.f;

    for (int k0 = 0; k0 < K; k0 += 16) {
        float4 av = *(const float4*)(A + (m0 + am) * K + k0 + ak);
        float4 bv = make_float4(0.f, 0.f, 0.f, 0.f);
        if (n0 + bn < N) bv = *(const float4*)(Bw + (k0 + bk) * N + n0 + bn);
        __syncthreads();
        As[ak + 0][am] = av.x;
        As[ak + 1][am] = av.y;
        As[ak + 2][am] = av.z;
        As[ak + 3][am] = av.w;
        *(float4*)&Bs[bk][bn] = bv;
        __syncthreads();
#pragma unroll
        for (int kk = 0; kk < 16; ++kk) {
            float4 a = *(const float4*)&As[kk][ty * 4];
            float4 bb = *(const float4*)&Bs[kk][tx * 4];
            float aa[4] = {a.x, a.y, a.z, a.w};
            float bbb[4] = {bb.x, bb.y, bb.z, bb.w};
#pragma unroll
            for (int i = 0; i < 4; ++i)
#pragma unroll
                for (int j = 0; j < 4; ++j)
                    acc[i][j] = fmaf(aa[i], bbb[j], acc[i][j]);
        }
    }
#pragma unroll
    for (int i = 0; i < 4; ++i) {
        int m = m0 + ty * 4 + i;
#pragma unroll
        for (int j = 0; j < 4; ++j) {
            int n = n0 + tx * 4 + j;
            if (n < N) {
                float v = acc[i][j] + bias[n];
                if (ACT == 0) v = fmaxf(v, 0.f);
                else          v = 1.f / (1.f + expf(-v));
                C[m * N + n] = v;
            }
        }
    }
}

// --------------------------------------------------------------------------
extern "C" void kernel_launch(void* const* d_in, const int* in_sizes, int n_in,
                              void* d_out, int out_size, void* d_ws, size_t ws_size,
                              hipStream_t stream) {
    const float* x   = (const float*)d_in[0];
    const float* w1  = (const float*)d_in[1];
    const float* b1  = (const float*)d_in[2];
    const float* pw  = (const float*)d_in[3];
    const float* pb  = (const float*)d_in[4];
    const float* rw  = (const float*)d_in[5];
    const float* dw1 = (const float*)d_in[6];
    const float* db1 = (const float*)d_in[7];
    const float* dw2 = (const float*)d_in[8];
    const float* db2 = (const float*)d_in[9];
    const float* dw3 = (const float*)d_in[10];
    const float* db3 = (const float*)d_in[11];
    float* out = (float*)d_out;
    char* wsb  = (char*)d_ws;
    if (ws_size < (size_t)WS_BYTES) return;

    h16*   hhi  = (h16*)(wsb + OFFB_HHI);
    h16*   wthi = (h16*)(wsb + OFFB_WTHI);
    h16*   w1t  = (h16*)(wsb + OFFB_WT1);
    float* Cbuf = (float*)(wsb + OFFB_C);
    h16*   pri  = (h16*)(wsb + OFFB_PRI);
    h16*   ut   = (h16*)(wsb + OFFB_UT);
    float* vbuf = (float*)(wsb + OFFB_V);
    float* d1   = (float*)(wsb + OFFB_D1);
    float* d2   = (float*)(wsb + OFFB_D2);

    prep_k<<<1504, 256, 0, stream>>>(w1, pw, w1t, wthi, Cbuf);
    conv1_mfma<<<3200, 256, 0, stream>>>(x, w1t, b1, hhi);
    prim_gemm_mfma<<<2304, 256, 0, stream>>>(hhi, wthi, Cbuf);
    squash_k<<<2304, 256, 0, stream>>>(Cbuf, pb, ut); // h region dead now
    priors_k<<<1440, 256, 0, stream>>>(ut, rw, pri);
    routing2_k<<<5120, 384, 0, stream>>>(pri, vbuf);
    dec1_k<<<512, 512, 0, stream>>>(vbuf, dw1, db1, out, d1);
    dec_gemm<0><<<128, 256, 0, stream>>>(d1, dw2, db2, d2, 512, 1024, 512);
    dec_gemm<1><<<104, 256, 0, stream>>>(d2, dw3, db3, out + 5120, 512, 784, 1024);
}

// Round 13
// 681.713 us; speedup vs baseline: 1.1682x; 1.0164x over previous
//
#include <hip/hip_runtime.h>
#include <math.h>

// ---------------------------------------------------------------------------
// CapsuleNet forward (round 30): internal route-node reorder n' = pos*32+ci
// and ut layout [b][n'] (was [n][b]).
// Mechanism: routing is permutation-equivariant over route nodes, so the
// internal node order is free. New layout makes:
//  - squash writes: 16B stores at ~300KB stride (4x sector inflation) ->
//    512B contiguous runs (lanes = consecutive ci).
//  - priors ut reads: 16B @ 8KB stride -> 128B contiguous per b.
//  - priors w-staging rows move to stride-36 in rw (read-once, negligible).
// routing2/dec1 untouched (slots symmetric). rw NOT permuted.
// History: r28 wsr16 (+68us), r29 delegated combine (+35us) -> 692.9us.
// Frozen: prim (297-303 floor, 7 mechanisms), conv1 (r22/26), prep (r27),
// dec1/dec_gemm (r12).
// ---------------------------------------------------------------------------

typedef _Float16 h16;
typedef h16 frag8 __attribute__((ext_vector_type(8)));    // 8 halves = 16 B
typedef h16 h16x4 __attribute__((ext_vector_type(4)));    // 4 halves = 8 B
typedef float f32x4 __attribute__((ext_vector_type(4)));

// workspace layout (BYTE offsets).
#define OFFB_HHI   0L             // 52428800 halves = 104857600 B
#define OFFB_WTHI  209715200L     // 5308416 halves = 10616832 B
#define OFFB_WT1   230948864L     // w1t: 24576 halves = 49152 B
#define OFFB_C     231031808L     // 4718592 floats -> end 249906176
#define WS_BYTES   249906176L
// aliased into dead h region after prim_gemm:
#define OFFB_PRI   0L             // 94371840 halves = 188743680 B (priors fp16)
#define OFFB_UT    188743680L     // 4718592 halves = 9437184 B -> OK
// aliased into dead wt region after prim_gemm:
#define OFFB_V     209715200L     // 81920 floats
#define OFFB_D1    210370560L     // 262144 floats
#define OFFB_D2    211419136L     // 524288 floats -> 213516288 OK

// async global->LDS, 16 B per lane. LDS dest must be lane-linear:
// lane i of a wave writes base + i*16 B.
#define GLL16(gp, lp)                                                        \
    __builtin_amdgcn_global_load_lds(                                        \
        (const __attribute__((address_space(1))) void*)(gp),                 \
        (__attribute__((address_space(3))) void*)(lp), 16, 0, 0)

// --------------------------------------------------------------------------
// wave reduce-scatter over 16 values: returns the FULL 64-lane sum of
// v[lane & 15]. 17 shfl (vs 96 for per-value butterfly). At xor-level b,
// keep the output whose bit b matches the lane bit, SEND the dropped one
// (partner symmetry: received value = partner's partial of the kept output).
__device__ __forceinline__ float wsr16(const float (&v)[16], int lane) {
    float t[8], u[4], w[2], z;
    int b0 = lane & 1, b1 = lane & 2, b2 = lane & 4, b3 = lane & 8;
#pragma unroll
    for (int j = 0; j < 8; ++j) {
        float k = b0 ? v[2 * j + 1] : v[2 * j];
        float s = b0 ? v[2 * j] : v[2 * j + 1];
        t[j] = k + __shfl_xor(s, 1);
    }
#pragma unroll
    for (int j = 0; j < 4; ++j) {
        float k = b1 ? t[2 * j + 1] : t[2 * j];
        float s = b1 ? t[2 * j] : t[2 * j + 1];
        u[j] = k + __shfl_xor(s, 2);
    }
#pragma unroll
    for (int j = 0; j < 2; ++j) {
        float k = b2 ? u[2 * j + 1] : u[2 * j];
        float s = b2 ? u[2 * j] : u[2 * j + 1];
        w[j] = k + __shfl_xor(s, 4);
    }
    {
        float k = b3 ? w[1] : w[0];
        float s = b3 ? w[0] : w[1];
        z = k + __shfl_xor(s, 8);
    }
    z += __shfl_xor(z, 16);
    z += __shfl_xor(z, 32);
    return z;
}

// --------------------------------------------------------------------------
// prep: blocks 0..95: w1t[oc][96] fp16 (k-padded); 96..351: prim B^T fp16;
// 352..1503: zero C via float4 (294912 float4/pass, 4 passes).
__global__ __launch_bounds__(256) void prep_k(const float* __restrict__ w1,
                                              const float* __restrict__ pw,
                                              h16* __restrict__ w1t,
                                              h16* __restrict__ whi,
                                              float* __restrict__ C) {
    __shared__ float s[2592];
    int bx = blockIdx.x, tid = threadIdx.x;
    if (bx < 96) {
        int k = bx, oc = tid;
        w1t[(long)oc * 96 + k] = (k < 81) ? (h16)w1[oc * 81 + k] : (h16)0.f;
    } else if (bx < 352) {
        int oc = bx - 96;
        long src0 = (long)oc * 20736, dst0 = src0;
        for (int ch = 0; ch < 8; ++ch) {
            int ic0 = ch * 32;
            __syncthreads();
            for (int e = tid; e < 2592; e += 256) s[e] = pw[src0 + ic0 * 81 + e];
            __syncthreads();
            for (int e = tid; e < 2592; e += 256) {
                int tap = e >> 5, icf = e & 31;
                whi[dst0 + tap * 256 + ic0 + icf] = (h16)s[icf * 81 + tap];
            }
        }
    } else {
        // 1152 blocks x 256 thr x 4 float4 = 4718592 floats exact
        float4* C4 = (float4*)C;
        long i = (long)(bx - 352) * 256 + tid;
        float4 z = make_float4(0.f, 0.f, 0.f, 0.f);
#pragma unroll
        for (int p = 0; p < 4; ++p) C4[i + (long)p * 294912] = z;
    }
}

// --------------------------------------------------------------------------
// conv1 as MFMA implicit-im2col GEMM. Grid 3200: nt = bx&1, mt = bx>>1.
// r22: pair-vectorized im2col + operand-swapped MFMA epilogue.
// r26: 3 blocks/CU + vectorized B-stage + setprio.
#define CLDK 104
__global__ __launch_bounds__(256, 3) void conv1_mfma(const float* __restrict__ x,
                                                     const h16* __restrict__ w1t,
                                                     const float* __restrict__ bias,
                                                     h16* __restrict__ hhi) {
    __shared__ h16 Al[128 * CLDK];
    __shared__ h16 Bw[128 * CLDK];
    int tid = threadIdx.x;
    int bx = blockIdx.x;
    int nt = bx & 1, mt = bx >> 1;
    int n0 = nt * 128;

    // B stage: thread = (oc = tid>>1, half = tid&1) copies 48 contiguous
    // halves (96 B) as 6 x 16B vector ops. No division, coalesced.
    {
        int oc = tid >> 1, half = tid & 1;
        const frag8* src = (const frag8*)(w1t + (long)(n0 + oc) * 96 + half * 48);
        frag8* dst = (frag8*)(&Bw[oc * CLDK + half * 48]);
#pragma unroll
        for (int v = 0; v < 6; ++v) dst[v] = src[v];
    }
    // A stage: one (ml, ky) pair per step -> 9 contiguous x floats.
    for (int p = tid; p < 128 * 9; p += 256) {
        int ml = p / 9, ky = p - (p / 9) * 9;
        int m = mt * 128 + ml;
        int b = m / 400, pix = m - b * 400;
        int oy = pix / 20, ox = pix - oy * 20;
        const float* xs = x + (long)b * 784 + (oy + ky) * 28 + ox;
        h16* dst = &Al[ml * CLDK + ky * 9];
#pragma unroll
        for (int kx = 0; kx < 9; ++kx) dst[kx] = (h16)xs[kx];
    }
    // zero the k = 81..95 pad (MFMA reads through k=95).
    for (int e = tid; e < 128 * 16; e += 256) {
        int ml = e >> 4, kz = 81 + (e & 15);
        if (kz < 96) Al[ml * CLDK + kz] = (h16)0.f;
    }
    __syncthreads();

    int wave = tid >> 6;
    int wm = wave >> 1, wn = wave & 1;
    int lane = tid & 63;
    int lm = lane & 15, quad = lane >> 4;

    f32x4 acc[4][4];   // acc[ni][mi]: D rows = oc (quad*4+r), cols = m (lm)
#pragma unroll
    for (int i = 0; i < 4; ++i)
#pragma unroll
        for (int j = 0; j < 4; ++j) acc[i][j] = (f32x4){0.f, 0.f, 0.f, 0.f};

#pragma unroll
    for (int ks = 0; ks < 3; ++ks) {
        int kc = ks * 32 + quad * 8;
        frag8 af[4], bf[4];
#pragma unroll
        for (int mi = 0; mi < 4; ++mi)
            af[mi] = *(const frag8*)&Al[(wm * 64 + mi * 16 + lm) * CLDK + kc];
#pragma unroll
        for (int ni = 0; ni < 4; ++ni)
            bf[ni] = *(const frag8*)&Bw[(wn * 64 + ni * 16 + lm) * CLDK + kc];
        // operand swap: first operand's lm-space (oc) -> D rows (quad*4+r),
        // second operand's lm-space (m) -> D cols (lm).
        __builtin_amdgcn_s_setprio(1);
#pragma unroll
        for (int ni = 0; ni < 4; ++ni)
#pragma unroll
            for (int mi = 0; mi < 4; ++mi)
                acc[ni][mi] = __builtin_amdgcn_mfma_f32_16x16x32_f16(
                    bf[ni], af[mi], acc[ni][mi], 0, 0, 0);
        __builtin_amdgcn_s_setprio(0);
    }

    // epilogue: lane owns oc = ocb..ocb+3 at fixed m -> one 8B store per
    // (ni,mi). Lanes {lm fixed, quad 0..3} form 32B contiguous segments.
#pragma unroll
    for (int ni = 0; ni < 4; ++ni) {
        int ocb = n0 + wn * 64 + ni * 16 + quad * 4;
        float4 bv = *(const float4*)(bias + ocb);
#pragma unroll
        for (int mi = 0; mi < 4; ++mi) {
            int m = mt * 128 + wm * 64 + mi * 16 + lm;
            h16x4 o;
            o[0] = (h16)fmaxf(acc[ni][mi][0] + bv.x, 0.f);
            o[1] = (h16)fmaxf(acc[ni][mi][1] + bv.y, 0.f);
            o[2] = (h16)fmaxf(acc[ni][mi][2] + bv.z, 0.f);
            o[3] = (h16)fmaxf(acc[ni][mi][3] + bv.w, 0.f);
            *(h16x4*)(hhi + (long)m * 256 + ocb) = o;
        }
    }
}

// --------------------------------------------------------------------------
// prim conv MFMA GEMM (round-24 EXACT, 297 us floor): BM=128 BN=128 BK=32,
// split-K x8 (kt = bx&7 -> XCD-pinned B slice). global_load_lds dwordx4
// into double-buffered LINEAR LDS [128][32]; one barrier per K-step;
// setprio(1) around MFMA cluster. Atomic accumulate into zeroed C.
__global__ __launch_bounds__(256, 4) void prim_gemm_mfma(
        const h16* __restrict__ Ahi, const h16* __restrict__ Bhi,
        float* __restrict__ C) {
    __shared__ __align__(16) h16 As[2][128 * 32];
    __shared__ __align__(16) h16 Bs[2][128 * 32];
    int tid = threadIdx.x;
    int bx = blockIdx.x;                  // 2304 blocks
    int kt = bx & 7;
    int nt = (bx >> 3) & 1;
    int mt = bx >> 4;                     // 0..143
    int n0 = nt * 128;
    int kb0 = kt * 81;

    int wave = tid >> 6;
    int wm = wave >> 1, wn = wave & 1;
    int lane = tid & 63;
    int lm = lane & 15, quad = lane >> 4;

    // staging geometry: thread t, chunk q in {0,1} covers LDS halves
    // [t*8 + q*2048, +8)  ->  row r = (t>>2) + q*64, col c = (t&3)*8.
    int c0 = (tid & 3) * 8;
    int r0 = tid >> 2;
    long abase0, abase1, bbase0, bbase1;
    {
        int m = mt * 128 + r0;
        int b = m / 36, pos = m - b * 36;
        int oy = pos / 6, ox = pos - oy * 6;
        abase0 = ((long)(b * 20 + 2 * oy) * 20 + 2 * ox) * 256 + c0;
        m = mt * 128 + r0 + 64;
        b = m / 36; pos = m - b * 36;
        oy = pos / 6; ox = pos - oy * 6;
        abase1 = ((long)(b * 20 + 2 * oy) * 20 + 2 * ox) * 256 + c0;
        bbase0 = (long)(n0 + r0) * 20736 + c0;
        bbase1 = (long)(n0 + r0 + 64) * 20736 + c0;
    }
    h16* la = &As[0][tid * 8];
    h16* lb = &Bs[0][tid * 8];

    auto stage = [&](int buf, int kb) {
        // wave-uniform K-step decode (lands in SGPRs)
        int tap = kb >> 3;
        int ic0 = (kb & 7) << 5;
        int ky = tap / 9, kx = tap - ky * 9;
        long aoff = (long)(ky * 20 + kx) * 256 + ic0;
        long boff = (long)kb * 32;
        long lo = (long)buf * 4096;       // halves per buffer
        GLL16(Ahi + abase0 + aoff, la + lo);
        GLL16(Ahi + abase1 + aoff, la + lo + 2048);
        GLL16(Bhi + bbase0 + boff, lb + lo);
        GLL16(Bhi + bbase1 + boff, lb + lo + 2048);
    };

    f32x4 acc[4][4];
#pragma unroll
    for (int i = 0; i < 4; ++i)
#pragma unroll
        for (int j = 0; j < 4; ++j) acc[i][j] = (f32x4){0.f, 0.f, 0.f, 0.f};

    stage(0, kb0);
    for (int it = 0; it < 81; ++it) {
        int cur = it & 1;
        // one barrier per K-step: drains vmcnt (buf[cur] staged) and lgkm
        // (prev iter's ds_reads of buf[cur^1] done before we overwrite it).
        __syncthreads();
        if (it + 1 < 81) stage(cur ^ 1, kb0 + it + 1);

        frag8 ah[4], bh[4];
#pragma unroll
        for (int mi = 0; mi < 4; ++mi) {
            int row = wm * 64 + mi * 16 + lm;
            ah[mi] = *(const frag8*)&As[cur][row * 32 + quad * 8];
        }
#pragma unroll
        for (int ni = 0; ni < 4; ++ni) {
            int col = wn * 64 + ni * 16 + lm;
            bh[ni] = *(const frag8*)&Bs[cur][col * 32 + quad * 8];
        }
        __builtin_amdgcn_s_setprio(1);
#pragma unroll
        for (int mi = 0; mi < 4; ++mi)
#pragma unroll
            for (int ni = 0; ni < 4; ++ni)
                acc[mi][ni] = __builtin_amdgcn_mfma_f32_16x16x32_f16(
                    ah[mi], bh[ni], acc[mi][ni], 0, 0, 0);
        __builtin_amdgcn_s_setprio(0);
    }

#pragma unroll
    for (int ni = 0; ni < 4; ++ni) {
        int n = n0 + wn * 64 + ni * 16 + lm;
#pragma unroll
        for (int mi = 0; mi < 4; ++mi) {
            int m = mt * 128 + wm * 64 + mi * 16 + quad * 4;
#pragma unroll
            for (int r = 0; r < 4; ++r)
                atomicAdd(&C[(long)(m + r) * 256 + n], acc[mi][ni][r]);
        }
    }
}

// --------------------------------------------------------------------------
// squash: C[(b*36+pos)][256] (+bias) -> ut[b][n'][8] fp16, n' = pos*32+ci.
// r30: lanes = consecutive ci -> 512B contiguous ut write runs.
__global__ void squash_k(const float* __restrict__ C,
                         const float* __restrict__ bias,
                         h16* __restrict__ ut) {
    int t = blockIdx.x * 256 + threadIdx.x;          // 589824 exact
    int row = t >> 5;                                 // (b*36+pos)
    int ci = t & 31;
    int b = row / 36, pos = row - b * 36;
    const float* src = C + (long)row * 256 + ci;
    float v[8]; float sn = 0.f;
#pragma unroll
    for (int i = 0; i < 8; ++i) {
        v[i] = src[i * 32] + bias[ci + i * 32];
        sn = fmaf(v[i], v[i], sn);
    }
    float scale = (sn / (1.f + sn)) / sqrtf(sn);
    frag8 o;
#pragma unroll
    for (int i = 0; i < 8; ++i) o[i] = (h16)(v[i] * scale);
    *(frag8*)(ut + ((long)b * 1152 + pos * 32 + ci) * 8) = o;
}

// --------------------------------------------------------------------------
// Phase A: priors[c,b,slot n'] = ut[b][n'] @ rw[c, n_orig(n')], fp16 out.
// Block ng covers n' = ng*8..+7 = fixed pos (= ng/4), ci = ci0..ci0+7
// (ci0 = (ng%4)*8); n_orig = ci*36 + pos. routing2 treats slots
// symmetrically, so the slot ordering is internal-only.
__global__ __launch_bounds__(256) void priors_k(const h16* __restrict__ ut,
                                                const float* __restrict__ rw,
                                                h16* __restrict__ priors) {
    int bid = blockIdx.x;                 // 1440 = 10 c * 144 n-groups
    int c = bid / 144, ng = bid - c * 144;
    int n0 = ng * 8;                      // n' base
    int pos = ng >> 2;
    int ci0 = (ng & 3) * 8;
    __shared__ float w[8][132];
    int tid = threadIdx.x;
    for (int e = tid; e < 1024; e += 256)
        w[e >> 7][e & 127] =
            rw[((long)c * 1152 + (ci0 + (e >> 7)) * 36 + pos) * 128 + (e & 127)];
    __syncthreads();
    int nl = tid & 7, bl = tid >> 3;      // bl 0..31
    for (int ch = 0; ch < 16; ++ch) {
        int b = ch * 32 + bl;
        frag8 uv = *(const frag8*)(ut + ((long)b * 1152 + n0 + nl) * 8);
        float uu[8];
#pragma unroll
        for (int i = 0; i < 8; ++i) uu[i] = (float)uv[i];
        float o[16];
#pragma unroll
        for (int j = 0; j < 16; ++j) o[j] = 0.f;
#pragma unroll
        for (int i = 0; i < 8; ++i)
#pragma unroll
            for (int j = 0; j < 16; ++j)
                o[j] = fmaf(uu[i], w[nl][i * 16 + j], o[j]);
        frag8 p0, p1;
#pragma unroll
        for (int j = 0; j < 8; ++j) { p0[j] = (h16)o[j]; p1[j] = (h16)o[j + 8]; }
        h16* dst = priors + ((long)(c * 512 + b) * 1152 + n0 + nl) * 16;
        *(frag8*)dst = p0;
        *(frag8*)(dst + 8) = p1;
    }
}

// --------------------------------------------------------------------------
// Phase B: 3-iter routing. Block per (c,b). it0 = exact uniform-softmax
// shortcut. r28: wsr16 reduce-scatter. r29: delegated cross-wave combine,
// vout broadcast via 4x ds_read_b128. (Slot order = n'; symmetric sums.)
__global__ __launch_bounds__(384) void routing2_k(const h16* __restrict__ priors,
                                                  float* __restrict__ vbuf) {
    int c = blockIdx.x >> 9;
    int b = blockIdx.x & 511;
    int tid = threadIdx.x;
    int wid = tid >> 6;
    int lane = tid & 63;
    __shared__ float wred[6][20];
    __shared__ float wmax[6];
    __shared__ __align__(16) float vsh[16];

    float pr[3][16];
#pragma unroll
    for (int r = 0; r < 3; ++r) {
        int n = tid + r * 384;
        const h16* pp = priors + ((long)(c * 512 + b) * 1152 + n) * 16;
        frag8 p0 = *(const frag8*)pp;
        frag8 p1 = *(const frag8*)(pp + 8);
#pragma unroll
        for (int o = 0; o < 8; ++o) { pr[r][o] = (float)p0[o]; pr[r][o + 8] = (float)p1[o]; }
    }

    float l0 = 0.f, l1 = 0.f, l2 = 0.f;
    float vout[16];

    // ---- iteration 0: probs uniform = 1/1152 ----
    {
        float red[16];
#pragma unroll
        for (int o = 0; o < 16; ++o) red[o] = pr[0][o] + pr[1][o] + pr[2][o];
        float z = wsr16(red, lane);           // full sum of output (lane&15)
        if (lane < 16) wred[wid][lane] = z;
        __syncthreads();
        if (tid < 16) {
            float s = wred[0][tid];
#pragma unroll
            for (int w = 1; w < 6; ++w) s += wred[w][tid];
            s *= (1.f / 1152.f);
            float sn = s * s;
            sn += __shfl_xor(sn, 1);
            sn += __shfl_xor(sn, 2);
            sn += __shfl_xor(sn, 4);
            sn += __shfl_xor(sn, 8);
            float scale = (sn / (1.f + sn)) / sqrtf(sn);
            vsh[tid] = s * scale;
        }
        __syncthreads();
        {
            const float4* vv = (const float4*)vsh;
            float4 a0 = vv[0], a1 = vv[1], a2 = vv[2], a3 = vv[3];
            vout[0]=a0.x; vout[1]=a0.y; vout[2]=a0.z; vout[3]=a0.w;
            vout[4]=a1.x; vout[5]=a1.y; vout[6]=a1.z; vout[7]=a1.w;
            vout[8]=a2.x; vout[9]=a2.y; vout[10]=a2.z; vout[11]=a2.w;
            vout[12]=a3.x; vout[13]=a3.y; vout[14]=a3.z; vout[15]=a3.w;
        }
        float d0 = 0.f, d1 = 0.f, d2 = 0.f;
#pragma unroll
        for (int o = 0; o < 16; ++o) {
            d0 = fmaf(pr[0][o], vout[o], d0);
            d1 = fmaf(pr[1][o], vout[o], d1);
            d2 = fmaf(pr[2][o], vout[o], d2);
        }
        l0 = d0; l1 = d1; l2 = d2;
    }

    // ---- iteration 1 (full softmax; updates l) ----
    {
        float lm = fmaxf(fmaxf(l0, l1), l2);
#pragma unroll
        for (int m = 32; m >= 1; m >>= 1) lm = fmaxf(lm, __shfl_xor(lm, m));
        if (lane == 0) wmax[wid] = lm;
        __syncthreads();                 // also retires it0's vsh reads
        float maxv = wmax[0];
#pragma unroll
        for (int w = 1; w < 6; ++w) maxv = fmaxf(maxv, wmax[w]);

        float e0 = expf(l0 - maxv), e1 = expf(l1 - maxv), e2 = expf(l2 - maxv);
        float red[16];
#pragma unroll
        for (int o = 0; o < 16; ++o)
            red[o] = fmaf(e0, pr[0][o], fmaf(e1, pr[1][o], e2 * pr[2][o]));
        float red16 = e0 + e1 + e2;
        float z = wsr16(red, lane);
#pragma unroll
        for (int m = 32; m >= 1; m >>= 1) red16 += __shfl_xor(red16, m);
        if (lane < 16) wred[wid][lane] = z;
        else if (lane == 16) wred[wid][16] = red16;
        __syncthreads();
        if (tid < 17) {
            float s = wred[0][tid];
#pragma unroll
            for (int w = 1; w < 6; ++w) s += wred[w][tid];
            float den = __shfl(s, 16);
            float inv = 1.f / den;
            float t = s * inv;
            float sn = t * t;
            sn += __shfl_xor(sn, 1);
            sn += __shfl_xor(sn, 2);
            sn += __shfl_xor(sn, 4);
            sn += __shfl_xor(sn, 8);
            float scale = (sn / (1.f + sn)) / sqrtf(sn);
            if (tid < 16) vsh[tid] = t * scale;
        }
        __syncthreads();
        {
            const float4* vv = (const float4*)vsh;
            float4 a0 = vv[0], a1 = vv[1], a2 = vv[2], a3 = vv[3];
            vout[0]=a0.x; vout[1]=a0.y; vout[2]=a0.z; vout[3]=a0.w;
            vout[4]=a1.x; vout[5]=a1.y; vout[6]=a1.z; vout[7]=a1.w;
            vout[8]=a2.x; vout[9]=a2.y; vout[10]=a2.z; vout[11]=a2.w;
            vout[12]=a3.x; vout[13]=a3.y; vout[14]=a3.z; vout[15]=a3.w;
        }
        float d0 = 0.f, d1 = 0.f, d2 = 0.f;
#pragma unroll
        for (int o = 0; o < 16; ++o) {
            d0 = fmaf(pr[0][o], vout[o], d0);
            d1 = fmaf(pr[1][o], vout[o], d1);
            d2 = fmaf(pr[2][o], vout[o], d2);
        }
        l0 += d0; l1 += d1; l2 += d2;
    }

    // ---- iteration 2 (final; vbuf written directly from stage 2) ----
    {
        float lm = fmaxf(fmaxf(l0, l1), l2);
#pragma unroll
        for (int m = 32; m >= 1; m >>= 1) lm = fmaxf(lm, __shfl_xor(lm, m));
        if (lane == 0) wmax[wid] = lm;
        __syncthreads();                 // retires it1's vsh reads
        float maxv = wmax[0];
#pragma unroll
        for (int w = 1; w < 6; ++w) maxv = fmaxf(maxv, wmax[w]);

        float e0 = expf(l0 - maxv), e1 = expf(l1 - maxv), e2 = expf(l2 - maxv);
        float red[16];
#pragma unroll
        for (int o = 0; o < 16; ++o)
            red[o] = fmaf(e0, pr[0][o], fmaf(e1, pr[1][o], e2 * pr[2][o]));
        float red16 = e0 + e1 + e2;
        float z = wsr16(red, lane);
#pragma unroll
        for (int m = 32; m >= 1; m >>= 1) red16 += __shfl_xor(red16, m);
        if (lane < 16) wred[wid][lane] = z;
        else if (lane == 16) wred[wid][16] = red16;
        __syncthreads();
        if (tid < 17) {
            float s = wred[0][tid];
#pragma unroll
            for (int w = 1; w < 6; ++w) s += wred[w][tid];
            float den = __shfl(s, 16);
            float inv = 1.f / den;
            float t = s * inv;
            float sn = t * t;
            sn += __shfl_xor(sn, 1);
            sn += __shfl_xor(sn, 2);
            sn += __shfl_xor(sn, 4);
            sn += __shfl_xor(sn, 8);
            float scale = (sn / (1.f + sn)) / sqrtf(sn);
            if (tid < 16) vbuf[(b * 10 + c) * 16 + tid] = t * scale;
        }
    }
}

// --------------------------------------------------------------------------
// dec1: fused classes/argmax/y_pred + sparse masked GEMM (K=16 of 160).
__global__ __launch_bounds__(512) void dec1_k(const float* __restrict__ vbuf,
                                              const float* __restrict__ dw1,
                                              const float* __restrict__ db1,
                                              float* __restrict__ out,
                                              float* __restrict__ d1) {
    __shared__ float sv[160];
    __shared__ float scls[10];
    __shared__ int sbest;
    int b = blockIdx.x, tid = threadIdx.x;
    if (tid < 160) sv[tid] = vbuf[b * 160 + tid];
    __syncthreads();
    if (tid < 10) {
        float sn = 0.f;
#pragma unroll
        for (int o = 0; o < 16; ++o) { float v = sv[tid * 16 + o]; sn = fmaf(v, v, sn); }
        scls[tid] = sqrtf(sn);
    }
    __syncthreads();
    if (tid == 0) {
        int best = 0; float bv = scls[0];
#pragma unroll
        for (int cc = 1; cc < 10; ++cc) if (scls[cc] > bv) { bv = scls[cc]; best = cc; }
        sbest = best;
    }
    __syncthreads();
    int best = sbest;
    if (tid < 10) {
        out[b * 10 + tid] = (tid == best) ? 1.f : 0.f;          // y_pred
        out[406528 + b * 10 + tid] = scls[tid];                 // classes
    }
    float acc = db1[tid];
    const float* wrow = dw1 + (long)best * 16 * 512;
#pragma unroll
    for (int i = 0; i < 16; ++i)
        acc = fmaf(sv[best * 16 + i], wrow[i * 512 + tid], acc);
    d1[(long)b * 512 + tid] = fmaxf(acc, 0.f);
}

// --------------------------------------------------------------------------
template <int ACT>
__global__ __launch_bounds__(256) void dec_gemm(const float* __restrict__ A,
                                                const float* __restrict__ Bw,
                                                const float* __restrict__ bias,
                                                float* __restrict__ C,
                                                int M, int N, int K) {
    __shared__ float As[16][68];
    __shared__ float Bs[16][68];
    int ntiles = (N + 63) >> 6;
    int mt = blockIdx.x / ntiles, nt = blockIdx.x - mt * ntiles;
    int m0 = mt * 64, n0 = nt * 64;
    int tid = threadIdx.x;
    int tx = tid & 15, ty = tid >> 4;
    int am = tid >> 2, ak = (tid & 3) * 4;
    int bk = tid >> 4, bn = (tid & 15) * 4;
    float acc[4][4];
#pragma unroll
    for (int i = 0; i < 4; ++i)
#pragma unroll
        for (int j = 0; j < 4; ++j) acc[i][j] = 0.f;

    for (int k0 = 0; k0 < K; k0 += 16) {
        float4 av = *(const float4*)(A + (m0 + am) * K + k0 + ak);
        float4 bv = make_float4(0.f, 0.f, 0.f, 0.f);
        if (n0 + bn < N) bv = *(const float4*)(Bw + (k0 + bk) * N + n0 + bn);
        __syncthreads();
        As[ak + 0][am] = av.x;
        As[ak + 1][am] = av.y;
        As[ak + 2][am] = av.z;
        As[ak + 3][am] = av.w;
        *(float4*)&Bs[bk][bn] = bv;
        __syncthreads();
#pragma unroll
        for (int kk = 0; kk < 16; ++kk) {
            float4 a = *(const float4*)&As[kk][ty * 4];
            float4 bb = *(const float4*)&Bs[kk][tx * 4];
            float aa[4] = {a.x, a.y, a.z, a.w};
            float bbb[4] = {bb.x, bb.y, bb.z, bb.w};
#pragma unroll
            for (int i = 0; i < 4; ++i)
#pragma unroll
                for (int j = 0; j < 4; ++j)
                    acc[i][j] = fmaf(aa[i], bbb[j], acc[i][j]);
        }
    }
#pragma unroll
    for (int i = 0; i < 4; ++i) {
        int m = m0 + ty * 4 + i;
#pragma unroll
        for (int j = 0; j < 4; ++j) {
            int n = n0 + tx * 4 + j;
            if (n < N) {
                float v = acc[i][j] + bias[n];
                if (ACT == 0) v = fmaxf(v, 0.f);
                else          v = 1.f / (1.f + expf(-v));
                C[m * N + n] = v;
            }
        }
    }
}

// --------------------------------------------------------------------------
extern "C" void kernel_launch(void* const* d_in, const int* in_sizes, int n_in,
                              void* d_out, int out_size, void* d_ws, size_t ws_size,
                              hipStream_t stream) {
    const float* x   = (const float*)d_in[0];
    const float* w1  = (const float*)d_in[1];
    const float* b1  = (const float*)d_in[2];
    const float* pw  = (const float*)d_in[3];
    const float* pb  = (const float*)d_in[4];
    const float* rw  = (const float*)d_in[5];
    const float* dw1 = (const float*)d_in[6];
    const float* db1 = (const float*)d_in[7];
    const float* dw2 = (const float*)d_in[8];
    const float* db2 = (const float*)d_in[9];
    const float* dw3 = (const float*)d_in[10];
    const float* db3 = (const float*)d_in[11];
    float* out = (float*)d_out;
    char* wsb  = (char*)d_ws;
    if (ws_size < (size_t)WS_BYTES) return;

    h16*   hhi  = (h16*)(wsb + OFFB_HHI);
    h16*   wthi = (h16*)(wsb + OFFB_WTHI);
    h16*   w1t  = (h16*)(wsb + OFFB_WT1);
    float* Cbuf = (float*)(wsb + OFFB_C);
    h16*   pri  = (h16*)(wsb + OFFB_PRI);
    h16*   ut   = (h16*)(wsb + OFFB_UT);
    float* vbuf = (float*)(wsb + OFFB_V);
    float* d1   = (float*)(wsb + OFFB_D1);
    float* d2   = (float*)(wsb + OFFB_D2);

    prep_k<<<1504, 256, 0, stream>>>(w1, pw, w1t, wthi, Cbuf);
    conv1_mfma<<<3200, 256, 0, stream>>>(x, w1t, b1, hhi);
    prim_gemm_mfma<<<2304, 256, 0, stream>>>(hhi, wthi, Cbuf);
    squash_k<<<2304, 256, 0, stream>>>(Cbuf, pb, ut); // h region dead now
    priors_k<<<1440, 256, 0, stream>>>(ut, rw, pri);
    routing2_k<<<5120, 384, 0, stream>>>(pri, vbuf);
    dec1_k<<<512, 512, 0, stream>>>(vbuf, dw1, db1, out, d1);
    dec_gemm<0><<<128, 256, 0, stream>>>(d1, dw2, db2, d2, 512, 1024, 512);
    dec_gemm<1><<<104, 256, 0, stream>>>(d2, dw3, db3, out + 5120, 512, 784, 1024);
}

// Round 14
// 636.520 us; speedup vs baseline: 1.2511x; 1.0710x over previous
//
#include <hip/hip_runtime.h>
#include <math.h>

// ---------------------------------------------------------------------------
// CapsuleNet forward (round 31): dec_gemm reworked (32x64 tiles + register
// prefetch double-buffer). Old shape: 64x64 tiles, grid 128/104 on 256 CUs
// (half idle, 1 wave/SIMD -> zero latency hiding), global load exposed
// between two barriers every K-step. New: grid 256/208 (full coverage),
// next-step A/B loads issued right after LDS publish -> overlap compute.
// History: r28 wsr16 (+68), r29 delegated combine (+35), r30 n'-reorder
// (+11) -> 681.7us. Frozen: prim (297-303 floor), conv1 (r22/26),
// prep (r27), squash/priors [b][n'] (r30), routing2 (r28/29), dec1 (r12).
// ---------------------------------------------------------------------------

typedef _Float16 h16;
typedef h16 frag8 __attribute__((ext_vector_type(8)));    // 8 halves = 16 B
typedef h16 h16x4 __attribute__((ext_vector_type(4)));    // 4 halves = 8 B
typedef float f32x4 __attribute__((ext_vector_type(4)));

// workspace layout (BYTE offsets).
#define OFFB_HHI   0L             // 52428800 halves = 104857600 B
#define OFFB_WTHI  209715200L     // 5308416 halves = 10616832 B
#define OFFB_WT1   230948864L     // w1t: 24576 halves = 49152 B
#define OFFB_C     231031808L     // 4718592 floats -> end 249906176
#define WS_BYTES   249906176L
// aliased into dead h region after prim_gemm:
#define OFFB_PRI   0L             // 94371840 halves = 188743680 B (priors fp16)
#define OFFB_UT    188743680L     // 4718592 halves = 9437184 B -> OK
// aliased into dead wt region after prim_gemm:
#define OFFB_V     209715200L     // 81920 floats
#define OFFB_D1    210370560L     // 262144 floats
#define OFFB_D2    211419136L     // 524288 floats -> 213516288 OK

// async global->LDS, 16 B per lane. LDS dest must be lane-linear:
// lane i of a wave writes base + i*16 B.
#define GLL16(gp, lp)                                                        \
    __builtin_amdgcn_global_load_lds(                                        \
        (const __attribute__((address_space(1))) void*)(gp),                 \
        (__attribute__((address_space(3))) void*)(lp), 16, 0, 0)

// --------------------------------------------------------------------------
// wave reduce-scatter over 16 values: returns the FULL 64-lane sum of
// v[lane & 15]. 17 shfl (vs 96 for per-value butterfly). At xor-level b,
// keep the output whose bit b matches the lane bit, SEND the dropped one
// (partner symmetry: received value = partner's partial of the kept output).
__device__ __forceinline__ float wsr16(const float (&v)[16], int lane) {
    float t[8], u[4], w[2], z;
    int b0 = lane & 1, b1 = lane & 2, b2 = lane & 4, b3 = lane & 8;
#pragma unroll
    for (int j = 0; j < 8; ++j) {
        float k = b0 ? v[2 * j + 1] : v[2 * j];
        float s = b0 ? v[2 * j] : v[2 * j + 1];
        t[j] = k + __shfl_xor(s, 1);
    }
#pragma unroll
    for (int j = 0; j < 4; ++j) {
        float k = b1 ? t[2 * j + 1] : t[2 * j];
        float s = b1 ? t[2 * j] : t[2 * j + 1];
        u[j] = k + __shfl_xor(s, 2);
    }
#pragma unroll
    for (int j = 0; j < 2; ++j) {
        float k = b2 ? u[2 * j + 1] : u[2 * j];
        float s = b2 ? u[2 * j] : u[2 * j + 1];
        w[j] = k + __shfl_xor(s, 4);
    }
    {
        float k = b3 ? w[1] : w[0];
        float s = b3 ? w[0] : w[1];
        z = k + __shfl_xor(s, 8);
    }
    z += __shfl_xor(z, 16);
    z += __shfl_xor(z, 32);
    return z;
}

// --------------------------------------------------------------------------
// prep: blocks 0..95: w1t[oc][96] fp16 (k-padded); 96..351: prim B^T fp16;
// 352..1503: zero C via float4 (294912 float4/pass, 4 passes).
__global__ __launch_bounds__(256) void prep_k(const float* __restrict__ w1,
                                              const float* __restrict__ pw,
                                              h16* __restrict__ w1t,
                                              h16* __restrict__ whi,
                                              float* __restrict__ C) {
    __shared__ float s[2592];
    int bx = blockIdx.x, tid = threadIdx.x;
    if (bx < 96) {
        int k = bx, oc = tid;
        w1t[(long)oc * 96 + k] = (k < 81) ? (h16)w1[oc * 81 + k] : (h16)0.f;
    } else if (bx < 352) {
        int oc = bx - 96;
        long src0 = (long)oc * 20736, dst0 = src0;
        for (int ch = 0; ch < 8; ++ch) {
            int ic0 = ch * 32;
            __syncthreads();
            for (int e = tid; e < 2592; e += 256) s[e] = pw[src0 + ic0 * 81 + e];
            __syncthreads();
            for (int e = tid; e < 2592; e += 256) {
                int tap = e >> 5, icf = e & 31;
                whi[dst0 + tap * 256 + ic0 + icf] = (h16)s[icf * 81 + tap];
            }
        }
    } else {
        // 1152 blocks x 256 thr x 4 float4 = 4718592 floats exact
        float4* C4 = (float4*)C;
        long i = (long)(bx - 352) * 256 + tid;
        float4 z = make_float4(0.f, 0.f, 0.f, 0.f);
#pragma unroll
        for (int p = 0; p < 4; ++p) C4[i + (long)p * 294912] = z;
    }
}

// --------------------------------------------------------------------------
// conv1 as MFMA implicit-im2col GEMM. Grid 3200: nt = bx&1, mt = bx>>1.
// r22: pair-vectorized im2col + operand-swapped MFMA epilogue.
// r26: 3 blocks/CU + vectorized B-stage + setprio.
#define CLDK 104
__global__ __launch_bounds__(256, 3) void conv1_mfma(const float* __restrict__ x,
                                                     const h16* __restrict__ w1t,
                                                     const float* __restrict__ bias,
                                                     h16* __restrict__ hhi) {
    __shared__ h16 Al[128 * CLDK];
    __shared__ h16 Bw[128 * CLDK];
    int tid = threadIdx.x;
    int bx = blockIdx.x;
    int nt = bx & 1, mt = bx >> 1;
    int n0 = nt * 128;

    // B stage: thread = (oc = tid>>1, half = tid&1) copies 48 contiguous
    // halves (96 B) as 6 x 16B vector ops. No division, coalesced.
    {
        int oc = tid >> 1, half = tid & 1;
        const frag8* src = (const frag8*)(w1t + (long)(n0 + oc) * 96 + half * 48);
        frag8* dst = (frag8*)(&Bw[oc * CLDK + half * 48]);
#pragma unroll
        for (int v = 0; v < 6; ++v) dst[v] = src[v];
    }
    // A stage: one (ml, ky) pair per step -> 9 contiguous x floats.
    for (int p = tid; p < 128 * 9; p += 256) {
        int ml = p / 9, ky = p - (p / 9) * 9;
        int m = mt * 128 + ml;
        int b = m / 400, pix = m - b * 400;
        int oy = pix / 20, ox = pix - oy * 20;
        const float* xs = x + (long)b * 784 + (oy + ky) * 28 + ox;
        h16* dst = &Al[ml * CLDK + ky * 9];
#pragma unroll
        for (int kx = 0; kx < 9; ++kx) dst[kx] = (h16)xs[kx];
    }
    // zero the k = 81..95 pad (MFMA reads through k=95).
    for (int e = tid; e < 128 * 16; e += 256) {
        int ml = e >> 4, kz = 81 + (e & 15);
        if (kz < 96) Al[ml * CLDK + kz] = (h16)0.f;
    }
    __syncthreads();

    int wave = tid >> 6;
    int wm = wave >> 1, wn = wave & 1;
    int lane = tid & 63;
    int lm = lane & 15, quad = lane >> 4;

    f32x4 acc[4][4];   // acc[ni][mi]: D rows = oc (quad*4+r), cols = m (lm)
#pragma unroll
    for (int i = 0; i < 4; ++i)
#pragma unroll
        for (int j = 0; j < 4; ++j) acc[i][j] = (f32x4){0.f, 0.f, 0.f, 0.f};

#pragma unroll
    for (int ks = 0; ks < 3; ++ks) {
        int kc = ks * 32 + quad * 8;
        frag8 af[4], bf[4];
#pragma unroll
        for (int mi = 0; mi < 4; ++mi)
            af[mi] = *(const frag8*)&Al[(wm * 64 + mi * 16 + lm) * CLDK + kc];
#pragma unroll
        for (int ni = 0; ni < 4; ++ni)
            bf[ni] = *(const frag8*)&Bw[(wn * 64 + ni * 16 + lm) * CLDK + kc];
        // operand swap: first operand's lm-space (oc) -> D rows (quad*4+r),
        // second operand's lm-space (m) -> D cols (lm).
        __builtin_amdgcn_s_setprio(1);
#pragma unroll
        for (int ni = 0; ni < 4; ++ni)
#pragma unroll
            for (int mi = 0; mi < 4; ++mi)
                acc[ni][mi] = __builtin_amdgcn_mfma_f32_16x16x32_f16(
                    bf[ni], af[mi], acc[ni][mi], 0, 0, 0);
        __builtin_amdgcn_s_setprio(0);
    }

    // epilogue: lane owns oc = ocb..ocb+3 at fixed m -> one 8B store per
    // (ni,mi). Lanes {lm fixed, quad 0..3} form 32B contiguous segments.
#pragma unroll
    for (int ni = 0; ni < 4; ++ni) {
        int ocb = n0 + wn * 64 + ni * 16 + quad * 4;
        float4 bv = *(const float4*)(bias + ocb);
#pragma unroll
        for (int mi = 0; mi < 4; ++mi) {
            int m = mt * 128 + wm * 64 + mi * 16 + lm;
            h16x4 o;
            o[0] = (h16)fmaxf(acc[ni][mi][0] + bv.x, 0.f);
            o[1] = (h16)fmaxf(acc[ni][mi][1] + bv.y, 0.f);
            o[2] = (h16)fmaxf(acc[ni][mi][2] + bv.z, 0.f);
            o[3] = (h16)fmaxf(acc[ni][mi][3] + bv.w, 0.f);
            *(h16x4*)(hhi + (long)m * 256 + ocb) = o;
        }
    }
}

// --------------------------------------------------------------------------
// prim conv MFMA GEMM (round-24 EXACT, 297 us floor): BM=128 BN=128 BK=32,
// split-K x8 (kt = bx&7 -> XCD-pinned B slice). global_load_lds dwordx4
// into double-buffered LINEAR LDS [128][32]; one barrier per K-step;
// setprio(1) around MFMA cluster. Atomic accumulate into zeroed C.
__global__ __launch_bounds__(256, 4) void prim_gemm_mfma(
        const h16* __restrict__ Ahi, const h16* __restrict__ Bhi,
        float* __restrict__ C) {
    __shared__ __align__(16) h16 As[2][128 * 32];
    __shared__ __align__(16) h16 Bs[2][128 * 32];
    int tid = threadIdx.x;
    int bx = blockIdx.x;                  // 2304 blocks
    int kt = bx & 7;
    int nt = (bx >> 3) & 1;
    int mt = bx >> 4;                     // 0..143
    int n0 = nt * 128;
    int kb0 = kt * 81;

    int wave = tid >> 6;
    int wm = wave >> 1, wn = wave & 1;
    int lane = tid & 63;
    int lm = lane & 15, quad = lane >> 4;

    // staging geometry: thread t, chunk q in {0,1} covers LDS halves
    // [t*8 + q*2048, +8)  ->  row r = (t>>2) + q*64, col c = (t&3)*8.
    int c0 = (tid & 3) * 8;
    int r0 = tid >> 2;
    long abase0, abase1, bbase0, bbase1;
    {
        int m = mt * 128 + r0;
        int b = m / 36, pos = m - b * 36;
        int oy = pos / 6, ox = pos - oy * 6;
        abase0 = ((long)(b * 20 + 2 * oy) * 20 + 2 * ox) * 256 + c0;
        m = mt * 128 + r0 + 64;
        b = m / 36; pos = m - b * 36;
        oy = pos / 6; ox = pos - oy * 6;
        abase1 = ((long)(b * 20 + 2 * oy) * 20 + 2 * ox) * 256 + c0;
        bbase0 = (long)(n0 + r0) * 20736 + c0;
        bbase1 = (long)(n0 + r0 + 64) * 20736 + c0;
    }
    h16* la = &As[0][tid * 8];
    h16* lb = &Bs[0][tid * 8];

    auto stage = [&](int buf, int kb) {
        // wave-uniform K-step decode (lands in SGPRs)
        int tap = kb >> 3;
        int ic0 = (kb & 7) << 5;
        int ky = tap / 9, kx = tap - ky * 9;
        long aoff = (long)(ky * 20 + kx) * 256 + ic0;
        long boff = (long)kb * 32;
        long lo = (long)buf * 4096;       // halves per buffer
        GLL16(Ahi + abase0 + aoff, la + lo);
        GLL16(Ahi + abase1 + aoff, la + lo + 2048);
        GLL16(Bhi + bbase0 + boff, lb + lo);
        GLL16(Bhi + bbase1 + boff, lb + lo + 2048);
    };

    f32x4 acc[4][4];
#pragma unroll
    for (int i = 0; i < 4; ++i)
#pragma unroll
        for (int j = 0; j < 4; ++j) acc[i][j] = (f32x4){0.f, 0.f, 0.f, 0.f};

    stage(0, kb0);
    for (int it = 0; it < 81; ++it) {
        int cur = it & 1;
        // one barrier per K-step: drains vmcnt (buf[cur] staged) and lgkm
        // (prev iter's ds_reads of buf[cur^1] done before we overwrite it).
        __syncthreads();
        if (it + 1 < 81) stage(cur ^ 1, kb0 + it + 1);

        frag8 ah[4], bh[4];
#pragma unroll
        for (int mi = 0; mi < 4; ++mi) {
            int row = wm * 64 + mi * 16 + lm;
            ah[mi] = *(const frag8*)&As[cur][row * 32 + quad * 8];
        }
#pragma unroll
        for (int ni = 0; ni < 4; ++ni) {
            int col = wn * 64 + ni * 16 + lm;
            bh[ni] = *(const frag8*)&Bs[cur][col * 32 + quad * 8];
        }
        __builtin_amdgcn_s_setprio(1);
#pragma unroll
        for (int mi = 0; mi < 4; ++mi)
#pragma unroll
            for (int ni = 0; ni < 4; ++ni)
                acc[mi][ni] = __builtin_amdgcn_mfma_f32_16x16x32_f16(
                    ah[mi], bh[ni], acc[mi][ni], 0, 0, 0);
        __builtin_amdgcn_s_setprio(0);
    }

#pragma unroll
    for (int ni = 0; ni < 4; ++ni) {
        int n = n0 + wn * 64 + ni * 16 + lm;
#pragma unroll
        for (int mi = 0; mi < 4; ++mi) {
            int m = mt * 128 + wm * 64 + mi * 16 + quad * 4;
#pragma unroll
            for (int r = 0; r < 4; ++r)
                atomicAdd(&C[(long)(m + r) * 256 + n], acc[mi][ni][r]);
        }
    }
}

// --------------------------------------------------------------------------
// squash: C[(b*36+pos)][256] (+bias) -> ut[b][n'][8] fp16, n' = pos*32+ci.
// r30: lanes = consecutive ci -> 512B contiguous ut write runs.
__global__ void squash_k(const float* __restrict__ C,
                         const float* __restrict__ bias,
                         h16* __restrict__ ut) {
    int t = blockIdx.x * 256 + threadIdx.x;          // 589824 exact
    int row = t >> 5;                                 // (b*36+pos)
    int ci = t & 31;
    int b = row / 36, pos = row - b * 36;
    const float* src = C + (long)row * 256 + ci;
    float v[8]; float sn = 0.f;
#pragma unroll
    for (int i = 0; i < 8; ++i) {
        v[i] = src[i * 32] + bias[ci + i * 32];
        sn = fmaf(v[i], v[i], sn);
    }
    float scale = (sn / (1.f + sn)) / sqrtf(sn);
    frag8 o;
#pragma unroll
    for (int i = 0; i < 8; ++i) o[i] = (h16)(v[i] * scale);
    *(frag8*)(ut + ((long)b * 1152 + pos * 32 + ci) * 8) = o;
}

// --------------------------------------------------------------------------
// Phase A: priors[c,b,slot n'] = ut[b][n'] @ rw[c, n_orig(n')], fp16 out.
// Block ng covers n' = ng*8..+7 = fixed pos (= ng/4), ci = ci0..ci0+7
// (ci0 = (ng%4)*8); n_orig = ci*36 + pos. routing2 treats slots
// symmetrically, so the slot ordering is internal-only.
__global__ __launch_bounds__(256) void priors_k(const h16* __restrict__ ut,
                                                const float* __restrict__ rw,
                                                h16* __restrict__ priors) {
    int bid = blockIdx.x;                 // 1440 = 10 c * 144 n-groups
    int c = bid / 144, ng = bid - c * 144;
    int n0 = ng * 8;                      // n' base
    int pos = ng >> 2;
    int ci0 = (ng & 3) * 8;
    __shared__ float w[8][132];
    int tid = threadIdx.x;
    for (int e = tid; e < 1024; e += 256)
        w[e >> 7][e & 127] =
            rw[((long)c * 1152 + (ci0 + (e >> 7)) * 36 + pos) * 128 + (e & 127)];
    __syncthreads();
    int nl = tid & 7, bl = tid >> 3;      // bl 0..31
    for (int ch = 0; ch < 16; ++ch) {
        int b = ch * 32 + bl;
        frag8 uv = *(const frag8*)(ut + ((long)b * 1152 + n0 + nl) * 8);
        float uu[8];
#pragma unroll
        for (int i = 0; i < 8; ++i) uu[i] = (float)uv[i];
        float o[16];
#pragma unroll
        for (int j = 0; j < 16; ++j) o[j] = 0.f;
#pragma unroll
        for (int i = 0; i < 8; ++i)
#pragma unroll
            for (int j = 0; j < 16; ++j)
                o[j] = fmaf(uu[i], w[nl][i * 16 + j], o[j]);
        frag8 p0, p1;
#pragma unroll
        for (int j = 0; j < 8; ++j) { p0[j] = (h16)o[j]; p1[j] = (h16)o[j + 8]; }
        h16* dst = priors + ((long)(c * 512 + b) * 1152 + n0 + nl) * 16;
        *(frag8*)dst = p0;
        *(frag8*)(dst + 8) = p1;
    }
}

// --------------------------------------------------------------------------
// Phase B: 3-iter routing. Block per (c,b). it0 = exact uniform-softmax
// shortcut. r28: wsr16 reduce-scatter. r29: delegated cross-wave combine,
// vout broadcast via 4x ds_read_b128. (Slot order = n'; symmetric sums.)
__global__ __launch_bounds__(384) void routing2_k(const h16* __restrict__ priors,
                                                  float* __restrict__ vbuf) {
    int c = blockIdx.x >> 9;
    int b = blockIdx.x & 511;
    int tid = threadIdx.x;
    int wid = tid >> 6;
    int lane = tid & 63;
    __shared__ float wred[6][20];
    __shared__ float wmax[6];
    __shared__ __align__(16) float vsh[16];

    float pr[3][16];
#pragma unroll
    for (int r = 0; r < 3; ++r) {
        int n = tid + r * 384;
        const h16* pp = priors + ((long)(c * 512 + b) * 1152 + n) * 16;
        frag8 p0 = *(const frag8*)pp;
        frag8 p1 = *(const frag8*)(pp + 8);
#pragma unroll
        for (int o = 0; o < 8; ++o) { pr[r][o] = (float)p0[o]; pr[r][o + 8] = (float)p1[o]; }
    }

    float l0 = 0.f, l1 = 0.f, l2 = 0.f;
    float vout[16];

    // ---- iteration 0: probs uniform = 1/1152 ----
    {
        float red[16];
#pragma unroll
        for (int o = 0; o < 16; ++o) red[o] = pr[0][o] + pr[1][o] + pr[2][o];
        float z = wsr16(red, lane);           // full sum of output (lane&15)
        if (lane < 16) wred[wid][lane] = z;
        __syncthreads();
        if (tid < 16) {
            float s = wred[0][tid];
#pragma unroll
            for (int w = 1; w < 6; ++w) s += wred[w][tid];
            s *= (1.f / 1152.f);
            float sn = s * s;
            sn += __shfl_xor(sn, 1);
            sn += __shfl_xor(sn, 2);
            sn += __shfl_xor(sn, 4);
            sn += __shfl_xor(sn, 8);
            float scale = (sn / (1.f + sn)) / sqrtf(sn);
            vsh[tid] = s * scale;
        }
        __syncthreads();
        {
            const float4* vv = (const float4*)vsh;
            float4 a0 = vv[0], a1 = vv[1], a2 = vv[2], a3 = vv[3];
            vout[0]=a0.x; vout[1]=a0.y; vout[2]=a0.z; vout[3]=a0.w;
            vout[4]=a1.x; vout[5]=a1.y; vout[6]=a1.z; vout[7]=a1.w;
            vout[8]=a2.x; vout[9]=a2.y; vout[10]=a2.z; vout[11]=a2.w;
            vout[12]=a3.x; vout[13]=a3.y; vout[14]=a3.z; vout[15]=a3.w;
        }
        float d0 = 0.f, d1 = 0.f, d2 = 0.f;
#pragma unroll
        for (int o = 0; o < 16; ++o) {
            d0 = fmaf(pr[0][o], vout[o], d0);
            d1 = fmaf(pr[1][o], vout[o], d1);
            d2 = fmaf(pr[2][o], vout[o], d2);
        }
        l0 = d0; l1 = d1; l2 = d2;
    }

    // ---- iteration 1 (full softmax; updates l) ----
    {
        float lm = fmaxf(fmaxf(l0, l1), l2);
#pragma unroll
        for (int m = 32; m >= 1; m >>= 1) lm = fmaxf(lm, __shfl_xor(lm, m));
        if (lane == 0) wmax[wid] = lm;
        __syncthreads();                 // also retires it0's vsh reads
        float maxv = wmax[0];
#pragma unroll
        for (int w = 1; w < 6; ++w) maxv = fmaxf(maxv, wmax[w]);

        float e0 = expf(l0 - maxv), e1 = expf(l1 - maxv), e2 = expf(l2 - maxv);
        float red[16];
#pragma unroll
        for (int o = 0; o < 16; ++o)
            red[o] = fmaf(e0, pr[0][o], fmaf(e1, pr[1][o], e2 * pr[2][o]));
        float red16 = e0 + e1 + e2;
        float z = wsr16(red, lane);
#pragma unroll
        for (int m = 32; m >= 1; m >>= 1) red16 += __shfl_xor(red16, m);
        if (lane < 16) wred[wid][lane] = z;
        else if (lane == 16) wred[wid][16] = red16;
        __syncthreads();
        if (tid < 17) {
            float s = wred[0][tid];
#pragma unroll
            for (int w = 1; w < 6; ++w) s += wred[w][tid];
            float den = __shfl(s, 16);
            float inv = 1.f / den;
            float t = s * inv;
            float sn = t * t;
            sn += __shfl_xor(sn, 1);
            sn += __shfl_xor(sn, 2);
            sn += __shfl_xor(sn, 4);
            sn += __shfl_xor(sn, 8);
            float scale = (sn / (1.f + sn)) / sqrtf(sn);
            if (tid < 16) vsh[tid] = t * scale;
        }
        __syncthreads();
        {
            const float4* vv = (const float4*)vsh;
            float4 a0 = vv[0], a1 = vv[1], a2 = vv[2], a3 = vv[3];
            vout[0]=a0.x; vout[1]=a0.y; vout[2]=a0.z; vout[3]=a0.w;
            vout[4]=a1.x; vout[5]=a1.y; vout[6]=a1.z; vout[7]=a1.w;
            vout[8]=a2.x; vout[9]=a2.y; vout[10]=a2.z; vout[11]=a2.w;
            vout[12]=a3.x; vout[13]=a3.y; vout[14]=a3.z; vout[15]=a3.w;
        }
        float d0 = 0.f, d1 = 0.f, d2 = 0.f;
#pragma unroll
        for (int o = 0; o < 16; ++o) {
            d0 = fmaf(pr[0][o], vout[o], d0);
            d1 = fmaf(pr[1][o], vout[o], d1);
            d2 = fmaf(pr[2][o], vout[o], d2);
        }
        l0 += d0; l1 += d1; l2 += d2;
    }

    // ---- iteration 2 (final; vbuf written directly from stage 2) ----
    {
        float lm = fmaxf(fmaxf(l0, l1), l2);
#pragma unroll
        for (int m = 32; m >= 1; m >>= 1) lm = fmaxf(lm, __shfl_xor(lm, m));
        if (lane == 0) wmax[wid] = lm;
        __syncthreads();                 // retires it1's vsh reads
        float maxv = wmax[0];
#pragma unroll
        for (int w = 1; w < 6; ++w) maxv = fmaxf(maxv, wmax[w]);

        float e0 = expf(l0 - maxv), e1 = expf(l1 - maxv), e2 = expf(l2 - maxv);
        float red[16];
#pragma unroll
        for (int o = 0; o < 16; ++o)
            red[o] = fmaf(e0, pr[0][o], fmaf(e1, pr[1][o], e2 * pr[2][o]));
        float red16 = e0 + e1 + e2;
        float z = wsr16(red, lane);
#pragma unroll
        for (int m = 32; m >= 1; m >>= 1) red16 += __shfl_xor(red16, m);
        if (lane < 16) wred[wid][lane] = z;
        else if (lane == 16) wred[wid][16] = red16;
        __syncthreads();
        if (tid < 17) {
            float s = wred[0][tid];
#pragma unroll
            for (int w = 1; w < 6; ++w) s += wred[w][tid];
            float den = __shfl(s, 16);
            float inv = 1.f / den;
            float t = s * inv;
            float sn = t * t;
            sn += __shfl_xor(sn, 1);
            sn += __shfl_xor(sn, 2);
            sn += __shfl_xor(sn, 4);
            sn += __shfl_xor(sn, 8);
            float scale = (sn / (1.f + sn)) / sqrtf(sn);
            if (tid < 16) vbuf[(b * 10 + c) * 16 + tid] = t * scale;
        }
    }
}

// --------------------------------------------------------------------------
// dec1: fused classes/argmax/y_pred + sparse masked GEMM (K=16 of 160).
__global__ __launch_bounds__(512) void dec1_k(const float* __restrict__ vbuf,
                                              const float* __restrict__ dw1,
                                              const float* __restrict__ db1,
                                              float* __restrict__ out,
                                              float* __restrict__ d1) {
    __shared__ float sv[160];
    __shared__ float scls[10];
    __shared__ int sbest;
    int b = blockIdx.x, tid = threadIdx.x;
    if (tid < 160) sv[tid] = vbuf[b * 160 + tid];
    __syncthreads();
    if (tid < 10) {
        float sn = 0.f;
#pragma unroll
        for (int o = 0; o < 16; ++o) { float v = sv[tid * 16 + o]; sn = fmaf(v, v, sn); }
        scls[tid] = sqrtf(sn);
    }
    __syncthreads();
    if (tid == 0) {
        int best = 0; float bv = scls[0];
#pragma unroll
        for (int cc = 1; cc < 10; ++cc) if (scls[cc] > bv) { bv = scls[cc]; best = cc; }
        sbest = best;
    }
    __syncthreads();
    int best = sbest;
    if (tid < 10) {
        out[b * 10 + tid] = (tid == best) ? 1.f : 0.f;          // y_pred
        out[406528 + b * 10 + tid] = scls[tid];                 // classes
    }
    float acc = db1[tid];
    const float* wrow = dw1 + (long)best * 16 * 512;
#pragma unroll
    for (int i = 0; i < 16; ++i)
        acc = fmaf(sv[best * 16 + i], wrow[i * 512 + tid], acc);
    d1[(long)b * 512 + tid] = fmaxf(acc, 0.f);
}

// --------------------------------------------------------------------------
// dec_gemm (round 31): 32x64 tiles (grid 256/208, full CU coverage) +
// register prefetch double-buffer (next k0's loads issued right after the
// LDS publish barrier, overlapping the 16-kk FMA block).
template <int ACT>
__global__ __launch_bounds__(256) void dec_gemm(const float* __restrict__ A,
                                                const float* __restrict__ Bw,
                                                const float* __restrict__ bias,
                                                float* __restrict__ C,
                                                int M, int N, int K) {
    __shared__ float As[16][36];   // [k][m], 32 m + pad
    __shared__ float Bs[16][68];   // [k][n], 64 n + pad
    int ntiles = (N + 63) >> 6;
    int mt = blockIdx.x / ntiles, nt = blockIdx.x - mt * ntiles;
    int m0 = mt * 32, n0 = nt * 64;
    int tid = threadIdx.x;
    int tx = tid & 15, ty = tid >> 4;          // out: n quad 4, m pair 2
    int am = tid >> 3, ak = (tid & 7) * 2;     // A: 32 rows x 8 float2
    int bk = tid >> 4, bn = (tid & 15) * 4;    // B: 16 k x 16 float4
    float acc[2][4];
#pragma unroll
    for (int i = 0; i < 2; ++i)
#pragma unroll
        for (int j = 0; j < 4; ++j) acc[i][j] = 0.f;

    bool bok = (n0 + bn < N);
    float2 av = *(const float2*)(A + (m0 + am) * K + ak);
    float4 bv = bok ? *(const float4*)(Bw + bk * N + n0 + bn)
                    : make_float4(0.f, 0.f, 0.f, 0.f);

    for (int k0 = 0; k0 < K; k0 += 16) {
        __syncthreads();                 // prior iteration's LDS reads done
        As[ak + 0][am] = av.x;
        As[ak + 1][am] = av.y;
        *(float4*)&Bs[bk][bn] = bv;
        __syncthreads();                 // tile published
        if (k0 + 16 < K) {               // prefetch next tile (overlaps FMA)
            av = *(const float2*)(A + (m0 + am) * K + k0 + 16 + ak);
            bv = bok ? *(const float4*)(Bw + (k0 + 16 + bk) * N + n0 + bn)
                     : make_float4(0.f, 0.f, 0.f, 0.f);
        }
#pragma unroll
        for (int kk = 0; kk < 16; ++kk) {
            float2 a = *(const float2*)&As[kk][ty * 2];
            float4 b = *(const float4*)&Bs[kk][tx * 4];
            acc[0][0] = fmaf(a.x, b.x, acc[0][0]);
            acc[0][1] = fmaf(a.x, b.y, acc[0][1]);
            acc[0][2] = fmaf(a.x, b.z, acc[0][2]);
            acc[0][3] = fmaf(a.x, b.w, acc[0][3]);
            acc[1][0] = fmaf(a.y, b.x, acc[1][0]);
            acc[1][1] = fmaf(a.y, b.y, acc[1][1]);
            acc[1][2] = fmaf(a.y, b.z, acc[1][2]);
            acc[1][3] = fmaf(a.y, b.w, acc[1][3]);
        }
    }
#pragma unroll
    for (int i = 0; i < 2; ++i) {
        int m = m0 + ty * 2 + i;
#pragma unroll
        for (int j = 0; j < 4; ++j) {
            int n = n0 + tx * 4 + j;
            if (n < N) {
                float v = acc[i][j] + bias[n];
                if (ACT == 0) v = fmaxf(v, 0.f);
                else          v = 1.f / (1.f + expf(-v));
                C[m * N + n] = v;
            }
        }
    }
}

// --------------------------------------------------------------------------
extern "C" void kernel_launch(void* const* d_in, const int* in_sizes, int n_in,
                              void* d_out, int out_size, void* d_ws, size_t ws_size,
                              hipStream_t stream) {
    const float* x   = (const float*)d_in[0];
    const float* w1  = (const float*)d_in[1];
    const float* b1  = (const float*)d_in[2];
    const float* pw  = (const float*)d_in[3];
    const float* pb  = (const float*)d_in[4];
    const float* rw  = (const float*)d_in[5];
    const float* dw1 = (const float*)d_in[6];
    const float* db1 = (const float*)d_in[7];
    const float* dw2 = (const float*)d_in[8];
    const float* db2 = (const float*)d_in[9];
    const float* dw3 = (const float*)d_in[10];
    const float* db3 = (const float*)d_in[11];
    float* out = (float*)d_out;
    char* wsb  = (char*)d_ws;
    if (ws_size < (size_t)WS_BYTES) return;

    h16*   hhi  = (h16*)(wsb + OFFB_HHI);
    h16*   wthi = (h16*)(wsb + OFFB_WTHI);
    h16*   w1t  = (h16*)(wsb + OFFB_WT1);
    float* Cbuf = (float*)(wsb + OFFB_C);
    h16*   pri  = (h16*)(wsb + OFFB_PRI);
    h16*   ut   = (h16*)(wsb + OFFB_UT);
    float* vbuf = (float*)(wsb + OFFB_V);
    float* d1   = (float*)(wsb + OFFB_D1);
    float* d2   = (float*)(wsb + OFFB_D2);

    prep_k<<<1504, 256, 0, stream>>>(w1, pw, w1t, wthi, Cbuf);
    conv1_mfma<<<3200, 256, 0, stream>>>(x, w1t, b1, hhi);
    prim_gemm_mfma<<<2304, 256, 0, stream>>>(hhi, wthi, Cbuf);
    squash_k<<<2304, 256, 0, stream>>>(Cbuf, pb, ut); // h region dead now
    priors_k<<<1440, 256, 0, stream>>>(ut, rw, pri);
    routing2_k<<<5120, 384, 0, stream>>>(pri, vbuf);
    dec1_k<<<512, 512, 0, stream>>>(vbuf, dw1, db1, out, d1);
    dec_gemm<0><<<256, 256, 0, stream>>>(d1, dw2, db2, d2, 512, 1024, 512);
    dec_gemm<1><<<208, 256, 0, stream>>>(d2, dw3, db3, out + 5120, 512, 784, 1024);
}

// Round 17
// 630.402 us; speedup vs baseline: 1.2632x; 1.0097x over previous
//
#include <hip/hip_runtime.h>
#include <math.h>

// ---------------------------------------------------------------------------
// CapsuleNet forward (round 32, third submission after 2x broker timeout):
// conv1 A-stage im2col now expands from an LDS-resident x-tile instead of
// ~41 scalar global loads/thread. The block's <=2 source images (2x784 f32)
// are loaded as 392 coalesced float4 (~1.5/thread), converted to h16, and
// parked in the FREE pad columns 96..103 of Al and Bw (2x2KB; MFMA reads
// kc<96, B-stage cols<96, expansion writes cols<=80, zero-pad 81..95 ->
// pads untouched). LDS stays 53.25KB -> 3 blocks/CU preserved. +1 barrier.
// VMEM ops/thread 41 -> ~2.
// Closed permanently: priors<->routing fusion (5120 blocks x 590KB rw from
// L2 = 3GB @ 34TB/s = 88us > 60us HBM saved; matches r17's 400us failure).
// History: r28 wsr16 (+68), r29 combine (+35), r30 n'-reorder (+11),
// r31 dec_gemm 32x64+prefetch (+45) -> 636.5us.
// Frozen: prim (297-303 floor), prep (r27), squash/priors (r30),
// routing2 (r28/29), dec1 (r12), dec_gemm (r31).
// ---------------------------------------------------------------------------

typedef _Float16 h16;
typedef h16 frag8 __attribute__((ext_vector_type(8)));    // 8 halves = 16 B
typedef h16 h16x4 __attribute__((ext_vector_type(4)));    // 4 halves = 8 B
typedef float f32x4 __attribute__((ext_vector_type(4)));

// workspace layout (BYTE offsets).
#define OFFB_HHI   0L             // 52428800 halves = 104857600 B
#define OFFB_WTHI  209715200L     // 5308416 halves = 10616832 B
#define OFFB_WT1   230948864L     // w1t: 24576 halves = 49152 B
#define OFFB_C     231031808L     // 4718592 floats -> end 249906176
#define WS_BYTES   249906176L
// aliased into dead h region after prim_gemm:
#define OFFB_PRI   0L             // 94371840 halves = 188743680 B (priors fp16)
#define OFFB_UT    188743680L     // 4718592 halves = 9437184 B -> OK
// aliased into dead wt region after prim_gemm:
#define OFFB_V     209715200L     // 81920 floats
#define OFFB_D1    210370560L     // 262144 floats
#define OFFB_D2    211419136L     // 524288 floats -> 213516288 OK

// async global->LDS, 16 B per lane. LDS dest must be lane-linear:
// lane i of a wave writes base + i*16 B.
#define GLL16(gp, lp)                                                        \
    __builtin_amdgcn_global_load_lds(                                        \
        (const __attribute__((address_space(1))) void*)(gp),                 \
        (__attribute__((address_space(3))) void*)(lp), 16, 0, 0)

// --------------------------------------------------------------------------
// wave reduce-scatter over 16 values: returns the FULL 64-lane sum of
// v[lane & 15]. 17 shfl (vs 96 for per-value butterfly). At xor-level b,
// keep the output whose bit b matches the lane bit, SEND the dropped one
// (partner symmetry: received value = partner's partial of the kept output).
__device__ __forceinline__ float wsr16(const float (&v)[16], int lane) {
    float t[8], u[4], w[2], z;
    int b0 = lane & 1, b1 = lane & 2, b2 = lane & 4, b3 = lane & 8;
#pragma unroll
    for (int j = 0; j < 8; ++j) {
        float k = b0 ? v[2 * j + 1] : v[2 * j];
        float s = b0 ? v[2 * j] : v[2 * j + 1];
        t[j] = k + __shfl_xor(s, 1);
    }
#pragma unroll
    for (int j = 0; j < 4; ++j) {
        float k = b1 ? t[2 * j + 1] : t[2 * j];
        float s = b1 ? t[2 * j] : t[2 * j + 1];
        u[j] = k + __shfl_xor(s, 2);
    }
#pragma unroll
    for (int j = 0; j < 2; ++j) {
        float k = b2 ? u[2 * j + 1] : u[2 * j];
        float s = b2 ? u[2 * j] : u[2 * j + 1];
        w[j] = k + __shfl_xor(s, 4);
    }
    {
        float k = b3 ? w[1] : w[0];
        float s = b3 ? w[0] : w[1];
        z = k + __shfl_xor(s, 8);
    }
    z += __shfl_xor(z, 16);
    z += __shfl_xor(z, 32);
    return z;
}

// --------------------------------------------------------------------------
// prep: blocks 0..95: w1t[oc][96] fp16 (k-padded); 96..351: prim B^T fp16;
// 352..1503: zero C via float4 (294912 float4/pass, 4 passes).
__global__ __launch_bounds__(256) void prep_k(const float* __restrict__ w1,
                                              const float* __restrict__ pw,
                                              h16* __restrict__ w1t,
                                              h16* __restrict__ whi,
                                              float* __restrict__ C) {
    __shared__ float s[2592];
    int bx = blockIdx.x, tid = threadIdx.x;
    if (bx < 96) {
        int k = bx, oc = tid;
        w1t[(long)oc * 96 + k] = (k < 81) ? (h16)w1[oc * 81 + k] : (h16)0.f;
    } else if (bx < 352) {
        int oc = bx - 96;
        long src0 = (long)oc * 20736, dst0 = src0;
        for (int ch = 0; ch < 8; ++ch) {
            int ic0 = ch * 32;
            __syncthreads();
            for (int e = tid; e < 2592; e += 256) s[e] = pw[src0 + ic0 * 81 + e];
            __syncthreads();
            for (int e = tid; e < 2592; e += 256) {
                int tap = e >> 5, icf = e & 31;
                whi[dst0 + tap * 256 + ic0 + icf] = (h16)s[icf * 81 + tap];
            }
        }
    } else {
        // 1152 blocks x 256 thr x 4 float4 = 4718592 floats exact
        float4* C4 = (float4*)C;
        long i = (long)(bx - 352) * 256 + tid;
        float4 z = make_float4(0.f, 0.f, 0.f, 0.f);
#pragma unroll
        for (int p = 0; p < 4; ++p) C4[i + (long)p * 294912] = z;
    }
}

// --------------------------------------------------------------------------
// conv1 as MFMA implicit-im2col GEMM. Grid 3200: nt = bx&1, mt = bx>>1.
// r22: operand-swapped MFMA epilogue. r26: 3 blocks/CU + vectorized B-stage
// + setprio. r32: x-tile in LDS pad columns, im2col expands from LDS.
#define CLDK 104
__global__ __launch_bounds__(256, 3) void conv1_mfma(const float* __restrict__ x,
                                                     const h16* __restrict__ w1t,
                                                     const float* __restrict__ bias,
                                                     h16* __restrict__ hhi) {
    __shared__ h16 Al[128 * CLDK];
    __shared__ h16 Bw[128 * CLDK];
    int tid = threadIdx.x;
    int bx = blockIdx.x;
    int nt = bx & 1, mt = bx >> 1;
    int n0 = nt * 128;

    // B stage: thread = (oc = tid>>1, half = tid&1) copies 48 contiguous
    // halves (96 B) as 6 x 16B vector ops (cols 0..95 of Bw).
    {
        int oc = tid >> 1, half = tid & 1;
        const frag8* src = (const frag8*)(w1t + (long)(n0 + oc) * 96 + half * 48);
        frag8* dst = (frag8*)(&Bw[oc * CLDK + half * 48]);
#pragma unroll
        for (int v = 0; v < 6; ++v) dst[v] = src[v];
    }
    // x-tile load (r32): block spans images b0..b0+1; 2x784 floats as 392
    // coalesced float4 -> h16x4 into pad cols 96..103. 8-half block j
    // (idx = j*8..j*8+7) lives at (j<128 ? Al : Bw)[(j%128)*CLDK + 96].
    int b0 = (mt * 128) / 400;
    for (int e = tid; e < 392; e += 256) {
        int img = (e >= 196);
        int bb = b0 + img;
        float4 xv = (bb < 512)
            ? *(const float4*)(x + (long)bb * 784 + (e - img * 196) * 4)
            : make_float4(0.f, 0.f, 0.f, 0.f);
        int j = e >> 1;                    // 8-half block index
        int off = (e & 1) * 4;
        h16* base = (j < 128) ? &Al[j * CLDK + 96] : &Bw[(j - 128) * CLDK + 96];
        h16x4 hv;
        hv[0] = (h16)xv.x; hv[1] = (h16)xv.y; hv[2] = (h16)xv.z; hv[3] = (h16)xv.w;
        *(h16x4*)(base + off) = hv;
    }
    __syncthreads();                       // x-tile resident in pads

    // A expansion: per (ml,ky) read 9 h16 from the LDS x-tile (pads,
    // cols 96..103) and write Al cols ky*9..ky*9+8 (<= 80) -- disjoint
    // column ranges, no race with concurrent pad reads.
    for (int p = tid; p < 128 * 9; p += 256) {
        int ml = p / 9, ky = p - (p / 9) * 9;
        int m = mt * 128 + ml;
        int b = m / 400, pix = m - b * 400;
        int oy = pix / 20, ox = pix - oy * 20;
        int idx0 = (b - b0) * 784 + (oy + ky) * 28 + ox;
        h16* dst = &Al[ml * CLDK + ky * 9];
#pragma unroll
        for (int kx = 0; kx < 9; ++kx) {
            int idx = idx0 + kx;
            int j = idx >> 3, off = idx & 7;
            h16 v = (j < 128) ? Al[j * CLDK + 96 + off]
                              : Bw[(j - 128) * CLDK + 96 + off];
            dst[kx] = v;
        }
    }
    // zero the k = 81..95 pad (MFMA reads through k=95).
    for (int e = tid; e < 128 * 16; e += 256) {
        int ml = e >> 4, kz = 81 + (e & 15);
        if (kz < 96) Al[ml * CLDK + kz] = (h16)0.f;
    }
    __syncthreads();

    int wave = tid >> 6;
    int wm = wave >> 1, wn = wave & 1;
    int lane = tid & 63;
    int lm = lane & 15, quad = lane >> 4;

    f32x4 acc[4][4];   // acc[ni][mi]: D rows = oc (quad*4+r), cols = m (lm)
#pragma unroll
    for (int i = 0; i < 4; ++i)
#pragma unroll
        for (int j = 0; j < 4; ++j) acc[i][j] = (f32x4){0.f, 0.f, 0.f, 0.f};

#pragma unroll
    for (int ks = 0; ks < 3; ++ks) {
        int kc = ks * 32 + quad * 8;
        frag8 af[4], bf[4];
#pragma unroll
        for (int mi = 0; mi < 4; ++mi)
            af[mi] = *(const frag8*)&Al[(wm * 64 + mi * 16 + lm) * CLDK + kc];
#pragma unroll
        for (int ni = 0; ni < 4; ++ni)
            bf[ni] = *(const frag8*)&Bw[(wn * 64 + ni * 16 + lm) * CLDK + kc];
        // operand swap: first operand's lm-space (oc) -> D rows (quad*4+r),
        // second operand's lm-space (m) -> D cols (lm).
        __builtin_amdgcn_s_setprio(1);
#pragma unroll
        for (int ni = 0; ni < 4; ++ni)
#pragma unroll
            for (int mi = 0; mi < 4; ++mi)
                acc[ni][mi] = __builtin_amdgcn_mfma_f32_16x16x32_f16(
                    bf[ni], af[mi], acc[ni][mi], 0, 0, 0);
        __builtin_amdgcn_s_setprio(0);
    }

    // epilogue: lane owns oc = ocb..ocb+3 at fixed m -> one 8B store per
    // (ni,mi). Lanes {lm fixed, quad 0..3} form 32B contiguous segments.
#pragma unroll
    for (int ni = 0; ni < 4; ++ni) {
        int ocb = n0 + wn * 64 + ni * 16 + quad * 4;
        float4 bv = *(const float4*)(bias + ocb);
#pragma unroll
        for (int mi = 0; mi < 4; ++mi) {
            int m = mt * 128 + wm * 64 + mi * 16 + lm;
            h16x4 o;
            o[0] = (h16)fmaxf(acc[ni][mi][0] + bv.x, 0.f);
            o[1] = (h16)fmaxf(acc[ni][mi][1] + bv.y, 0.f);
            o[2] = (h16)fmaxf(acc[ni][mi][2] + bv.z, 0.f);
            o[3] = (h16)fmaxf(acc[ni][mi][3] + bv.w, 0.f);
            *(h16x4*)(hhi + (long)m * 256 + ocb) = o;
        }
    }
}

// --------------------------------------------------------------------------
// prim conv MFMA GEMM (round-24 EXACT, 297 us floor): BM=128 BN=128 BK=32,
// split-K x8 (kt = bx&7 -> XCD-pinned B slice). global_load_lds dwordx4
// into double-buffered LINEAR LDS [128][32]; one barrier per K-step;
// setprio(1) around MFMA cluster. Atomic accumulate into zeroed C.
__global__ __launch_bounds__(256, 4) void prim_gemm_mfma(
        const h16* __restrict__ Ahi, const h16* __restrict__ Bhi,
        float* __restrict__ C) {
    __shared__ __align__(16) h16 As[2][128 * 32];
    __shared__ __align__(16) h16 Bs[2][128 * 32];
    int tid = threadIdx.x;
    int bx = blockIdx.x;                  // 2304 blocks
    int kt = bx & 7;
    int nt = (bx >> 3) & 1;
    int mt = bx >> 4;                     // 0..143
    int n0 = nt * 128;
    int kb0 = kt * 81;

    int wave = tid >> 6;
    int wm = wave >> 1, wn = wave & 1;
    int lane = tid & 63;
    int lm = lane & 15, quad = lane >> 4;

    // staging geometry: thread t, chunk q in {0,1} covers LDS halves
    // [t*8 + q*2048, +8)  ->  row r = (t>>2) + q*64, col c = (t&3)*8.
    int c0 = (tid & 3) * 8;
    int r0 = tid >> 2;
    long abase0, abase1, bbase0, bbase1;
    {
        int m = mt * 128 + r0;
        int b = m / 36, pos = m - b * 36;
        int oy = pos / 6, ox = pos - oy * 6;
        abase0 = ((long)(b * 20 + 2 * oy) * 20 + 2 * ox) * 256 + c0;
        m = mt * 128 + r0 + 64;
        b = m / 36; pos = m - b * 36;
        oy = pos / 6; ox = pos - oy * 6;
        abase1 = ((long)(b * 20 + 2 * oy) * 20 + 2 * ox) * 256 + c0;
        bbase0 = (long)(n0 + r0) * 20736 + c0;
        bbase1 = (long)(n0 + r0 + 64) * 20736 + c0;
    }
    h16* la = &As[0][tid * 8];
    h16* lb = &Bs[0][tid * 8];

    auto stage = [&](int buf, int kb) {
        // wave-uniform K-step decode (lands in SGPRs)
        int tap = kb >> 3;
        int ic0 = (kb & 7) << 5;
        int ky = tap / 9, kx = tap - ky * 9;
        long aoff = (long)(ky * 20 + kx) * 256 + ic0;
        long boff = (long)kb * 32;
        long lo = (long)buf * 4096;       // halves per buffer
        GLL16(Ahi + abase0 + aoff, la + lo);
        GLL16(Ahi + abase1 + aoff, la + lo + 2048);
        GLL16(Bhi + bbase0 + boff, lb + lo);
        GLL16(Bhi + bbase1 + boff, lb + lo + 2048);
    };

    f32x4 acc[4][4];
#pragma unroll
    for (int i = 0; i < 4; ++i)
#pragma unroll
        for (int j = 0; j < 4; ++j) acc[i][j] = (f32x4){0.f, 0.f, 0.f, 0.f};

    stage(0, kb0);
    for (int it = 0; it < 81; ++it) {
        int cur = it & 1;
        // one barrier per K-step: drains vmcnt (buf[cur] staged) and lgkm
        // (prev iter's ds_reads of buf[cur^1] done before we overwrite it).
        __syncthreads();
        if (it + 1 < 81) stage(cur ^ 1, kb0 + it + 1);

        frag8 ah[4], bh[4];
#pragma unroll
        for (int mi = 0; mi < 4; ++mi) {
            int row = wm * 64 + mi * 16 + lm;
            ah[mi] = *(const frag8*)&As[cur][row * 32 + quad * 8];
        }
#pragma unroll
        for (int ni = 0; ni < 4; ++ni) {
            int col = wn * 64 + ni * 16 + lm;
            bh[ni] = *(const frag8*)&Bs[cur][col * 32 + quad * 8];
        }
        __builtin_amdgcn_s_setprio(1);
#pragma unroll
        for (int mi = 0; mi < 4; ++mi)
#pragma unroll
            for (int ni = 0; ni < 4; ++ni)
                acc[mi][ni] = __builtin_amdgcn_mfma_f32_16x16x32_f16(
                    ah[mi], bh[ni], acc[mi][ni], 0, 0, 0);
        __builtin_amdgcn_s_setprio(0);
    }

#pragma unroll
    for (int ni = 0; ni < 4; ++ni) {
        int n = n0 + wn * 64 + ni * 16 + lm;
#pragma unroll
        for (int mi = 0; mi < 4; ++mi) {
            int m = mt * 128 + wm * 64 + mi * 16 + quad * 4;
#pragma unroll
            for (int r = 0; r < 4; ++r)
                atomicAdd(&C[(long)(m + r) * 256 + n], acc[mi][ni][r]);
        }
    }
}

// --------------------------------------------------------------------------
// squash: C[(b*36+pos)][256] (+bias) -> ut[b][n'][8] fp16, n' = pos*32+ci.
// r30: lanes = consecutive ci -> 512B contiguous ut write runs.
__global__ void squash_k(const float* __restrict__ C,
                         const float* __restrict__ bias,
                         h16* __restrict__ ut) {
    int t = blockIdx.x * 256 + threadIdx.x;          // 589824 exact
    int row = t >> 5;                                 // (b*36+pos)
    int ci = t & 31;
    int b = row / 36, pos = row - b * 36;
    const float* src = C + (long)row * 256 + ci;
    float v[8]; float sn = 0.f;
#pragma unroll
    for (int i = 0; i < 8; ++i) {
        v[i] = src[i * 32] + bias[ci + i * 32];
        sn = fmaf(v[i], v[i], sn);
    }
    float scale = (sn / (1.f + sn)) / sqrtf(sn);
    frag8 o;
#pragma unroll
    for (int i = 0; i < 8; ++i) o[i] = (h16)(v[i] * scale);
    *(frag8*)(ut + ((long)b * 1152 + pos * 32 + ci) * 8) = o;
}

// --------------------------------------------------------------------------
// Phase A: priors[c,b,slot n'] = ut[b][n'] @ rw[c, n_orig(n')], fp16 out.
// Block ng covers n' = ng*8..+7 = fixed pos (= ng/4), ci = ci0..ci0+7
// (ci0 = (ng%4)*8); n_orig = ci*36 + pos. routing2 treats slots
// symmetrically, so the slot ordering is internal-only.
__global__ __launch_bounds__(256) void priors_k(const h16* __restrict__ ut,
                                                const float* __restrict__ rw,
                                                h16* __restrict__ priors) {
    int bid = blockIdx.x;                 // 1440 = 10 c * 144 n-groups
    int c = bid / 144, ng = bid - c * 144;
    int n0 = ng * 8;                      // n' base
    int pos = ng >> 2;
    int ci0 = (ng & 3) * 8;
    __shared__ float w[8][132];
    int tid = threadIdx.x;
    for (int e = tid; e < 1024; e += 256)
        w[e >> 7][e & 127] =
            rw[((long)c * 1152 + (ci0 + (e >> 7)) * 36 + pos) * 128 + (e & 127)];
    __syncthreads();
    int nl = tid & 7, bl = tid >> 3;      // bl 0..31
    for (int ch = 0; ch < 16; ++ch) {
        int b = ch * 32 + bl;
        frag8 uv = *(const frag8*)(ut + ((long)b * 1152 + n0 + nl) * 8);
        float uu[8];
#pragma unroll
        for (int i = 0; i < 8; ++i) uu[i] = (float)uv[i];
        float o[16];
#pragma unroll
        for (int j = 0; j < 16; ++j) o[j] = 0.f;
#pragma unroll
        for (int i = 0; i < 8; ++i)
#pragma unroll
            for (int j = 0; j < 16; ++j)
                o[j] = fmaf(uu[i], w[nl][i * 16 + j], o[j]);
        frag8 p0, p1;
#pragma unroll
        for (int j = 0; j < 8; ++j) { p0[j] = (h16)o[j]; p1[j] = (h16)o[j + 8]; }
        h16* dst = priors + ((long)(c * 512 + b) * 1152 + n0 + nl) * 16;
        *(frag8*)dst = p0;
        *(frag8*)(dst + 8) = p1;
    }
}

// --------------------------------------------------------------------------
// Phase B: 3-iter routing. Block per (c,b). it0 = exact uniform-softmax
// shortcut. r28: wsr16 reduce-scatter. r29: delegated cross-wave combine,
// vout broadcast via 4x ds_read_b128. (Slot order = n'; symmetric sums.)
__global__ __launch_bounds__(384) void routing2_k(const h16* __restrict__ priors,
                                                  float* __restrict__ vbuf) {
    int c = blockIdx.x >> 9;
    int b = blockIdx.x & 511;
    int tid = threadIdx.x;
    int wid = tid >> 6;
    int lane = tid & 63;
    __shared__ float wred[6][20];
    __shared__ float wmax[6];
    __shared__ __align__(16) float vsh[16];

    float pr[3][16];
#pragma unroll
    for (int r = 0; r < 3; ++r) {
        int n = tid + r * 384;
        const h16* pp = priors + ((long)(c * 512 + b) * 1152 + n) * 16;
        frag8 p0 = *(const frag8*)pp;
        frag8 p1 = *(const frag8*)(pp + 8);
#pragma unroll
        for (int o = 0; o < 8; ++o) { pr[r][o] = (float)p0[o]; pr[r][o + 8] = (float)p1[o]; }
    }

    float l0 = 0.f, l1 = 0.f, l2 = 0.f;
    float vout[16];

    // ---- iteration 0: probs uniform = 1/1152 ----
    {
        float red[16];
#pragma unroll
        for (int o = 0; o < 16; ++o) red[o] = pr[0][o] + pr[1][o] + pr[2][o];
        float z = wsr16(red, lane);           // full sum of output (lane&15)
        if (lane < 16) wred[wid][lane] = z;
        __syncthreads();
        if (tid < 16) {
            float s = wred[0][tid];
#pragma unroll
            for (int w = 1; w < 6; ++w) s += wred[w][tid];
            s *= (1.f / 1152.f);
            float sn = s * s;
            sn += __shfl_xor(sn, 1);
            sn += __shfl_xor(sn, 2);
            sn += __shfl_xor(sn, 4);
            sn += __shfl_xor(sn, 8);
            float scale = (sn / (1.f + sn)) / sqrtf(sn);
            vsh[tid] = s * scale;
        }
        __syncthreads();
        {
            const float4* vv = (const float4*)vsh;
            float4 a0 = vv[0], a1 = vv[1], a2 = vv[2], a3 = vv[3];
            vout[0]=a0.x; vout[1]=a0.y; vout[2]=a0.z; vout[3]=a0.w;
            vout[4]=a1.x; vout[5]=a1.y; vout[6]=a1.z; vout[7]=a1.w;
            vout[8]=a2.x; vout[9]=a2.y; vout[10]=a2.z; vout[11]=a2.w;
            vout[12]=a3.x; vout[13]=a3.y; vout[14]=a3.z; vout[15]=a3.w;
        }
        float d0 = 0.f, d1 = 0.f, d2 = 0.f;
#pragma unroll
        for (int o = 0; o < 16; ++o) {
            d0 = fmaf(pr[0][o], vout[o], d0);
            d1 = fmaf(pr[1][o], vout[o], d1);
            d2 = fmaf(pr[2][o], vout[o], d2);
        }
        l0 = d0; l1 = d1; l2 = d2;
    }

    // ---- iteration 1 (full softmax; updates l) ----
    {
        float lm = fmaxf(fmaxf(l0, l1), l2);
#pragma unroll
        for (int m = 32; m >= 1; m >>= 1) lm = fmaxf(lm, __shfl_xor(lm, m));
        if (lane == 0) wmax[wid] = lm;
        __syncthreads();                 // also retires it0's vsh reads
        float maxv = wmax[0];
#pragma unroll
        for (int w = 1; w < 6; ++w) maxv = fmaxf(maxv, wmax[w]);

        float e0 = expf(l0 - maxv), e1 = expf(l1 - maxv), e2 = expf(l2 - maxv);
        float red[16];
#pragma unroll
        for (int o = 0; o < 16; ++o)
            red[o] = fmaf(e0, pr[0][o], fmaf(e1, pr[1][o], e2 * pr[2][o]));
        float red16 = e0 + e1 + e2;
        float z = wsr16(red, lane);
#pragma unroll
        for (int m = 32; m >= 1; m >>= 1) red16 += __shfl_xor(red16, m);
        if (lane < 16) wred[wid][lane] = z;
        else if (lane == 16) wred[wid][16] = red16;
        __syncthreads();
        if (tid < 17) {
            float s = wred[0][tid];
#pragma unroll
            for (int w = 1; w < 6; ++w) s += wred[w][tid];
            float den = __shfl(s, 16);
            float inv = 1.f / den;
            float t = s * inv;
            float sn = t * t;
            sn += __shfl_xor(sn, 1);
            sn += __shfl_xor(sn, 2);
            sn += __shfl_xor(sn, 4);
            sn += __shfl_xor(sn, 8);
            float scale = (sn / (1.f + sn)) / sqrtf(sn);
            if (tid < 16) vsh[tid] = t * scale;
        }
        __syncthreads();
        {
            const float4* vv = (const float4*)vsh;
            float4 a0 = vv[0], a1 = vv[1], a2 = vv[2], a3 = vv[3];
            vout[0]=a0.x; vout[1]=a0.y; vout[2]=a0.z; vout[3]=a0.w;
            vout[4]=a1.x; vout[5]=a1.y; vout[6]=a1.z; vout[7]=a1.w;
            vout[8]=a2.x; vout[9]=a2.y; vout[10]=a2.z; vout[11]=a2.w;
            vout[12]=a3.x; vout[13]=a3.y; vout[14]=a3.z; vout[15]=a3.w;
        }
        float d0 = 0.f, d1 = 0.f, d2 = 0.f;
#pragma unroll
        for (int o = 0; o < 16; ++o) {
            d0 = fmaf(pr[0][o], vout[o], d0);
            d1 = fmaf(pr[1][o], vout[o], d1);
            d2 = fmaf(pr[2][o], vout[o], d2);
        }
        l0 += d0; l1 += d1; l2 += d2;
    }

    // ---- iteration 2 (final; vbuf written directly from stage 2) ----
    {
        float lm = fmaxf(fmaxf(l0, l1), l2);
#pragma unroll
        for (int m = 32; m >= 1; m >>= 1) lm = fmaxf(lm, __shfl_xor(lm, m));
        if (lane == 0) wmax[wid] = lm;
        __syncthreads();                 // retires it1's vsh reads
        float maxv = wmax[0];
#pragma unroll
        for (int w = 1; w < 6; ++w) maxv = fmaxf(maxv, wmax[w]);

        float e0 = expf(l0 - maxv), e1 = expf(l1 - maxv), e2 = expf(l2 - maxv);
        float red[16];
#pragma unroll
        for (int o = 0; o < 16; ++o)
            red[o] = fmaf(e0, pr[0][o], fmaf(e1, pr[1][o], e2 * pr[2][o]));
        float red16 = e0 + e1 + e2;
        float z = wsr16(red, lane);
#pragma unroll
        for (int m = 32; m >= 1; m >>= 1) red16 += __shfl_xor(red16, m);
        if (lane < 16) wred[wid][lane] = z;
        else if (lane == 16) wred[wid][16] = red16;
        __syncthreads();
        if (tid < 17) {
            float s = wred[0][tid];
#pragma unroll
            for (int w = 1; w < 6; ++w) s += wred[w][tid];
            float den = __shfl(s, 16);
            float inv = 1.f / den;
            float t = s * inv;
            float sn = t * t;
            sn += __shfl_xor(sn, 1);
            sn += __shfl_xor(sn, 2);
            sn += __shfl_xor(sn, 4);
            sn += __shfl_xor(sn, 8);
            float scale = (sn / (1.f + sn)) / sqrtf(sn);
            if (tid < 16) vbuf[(b * 10 + c) * 16 + tid] = t * scale;
        }
    }
}

// --------------------------------------------------------------------------
// dec1: fused classes/argmax/y_pred + sparse masked GEMM (K=16 of 160).
__global__ __launch_bounds__(512) void dec1_k(const float* __restrict__ vbuf,
                                              const float* __restrict__ dw1,
                                              const float* __restrict__ db1,
                                              float* __restrict__ out,
                                              float* __restrict__ d1) {
    __shared__ float sv[160];
    __shared__ float scls[10];
    __shared__ int sbest;
    int b = blockIdx.x, tid = threadIdx.x;
    if (tid < 160) sv[tid] = vbuf[b * 160 + tid];
    __syncthreads();
    if (tid < 10) {
        float sn = 0.f;
#pragma unroll
        for (int o = 0; o < 16; ++o) { float v = sv[tid * 16 + o]; sn = fmaf(v, v, sn); }
        scls[tid] = sqrtf(sn);
    }
    __syncthreads();
    if (tid == 0) {
        int best = 0; float bv = scls[0];
#pragma unroll
        for (int cc = 1; cc < 10; ++cc) if (scls[cc] > bv) { bv = scls[cc]; best = cc; }
        sbest = best;
    }
    __syncthreads();
    int best = sbest;
    if (tid < 10) {
        out[b * 10 + tid] = (tid == best) ? 1.f : 0.f;          // y_pred
        out[406528 + b * 10 + tid] = scls[tid];                 // classes
    }
    float acc = db1[tid];
    const float* wrow = dw1 + (long)best * 16 * 512;
#pragma unroll
    for (int i = 0; i < 16; ++i)
        acc = fmaf(sv[best * 16 + i], wrow[i * 512 + tid], acc);
    d1[(long)b * 512 + tid] = fmaxf(acc, 0.f);
}

// --------------------------------------------------------------------------
// dec_gemm (round 31): 32x64 tiles (grid 256/208, full CU coverage) +
// register prefetch double-buffer (next k0's loads issued right after the
// LDS publish barrier, overlapping the 16-kk FMA block).
template <int ACT>
__global__ __launch_bounds__(256) void dec_gemm(const float* __restrict__ A,
                                                const float* __restrict__ Bw,
                                                const float* __restrict__ bias,
                                                float* __restrict__ C,
                                                int M, int N, int K) {
    __shared__ float As[16][36];   // [k][m], 32 m + pad
    __shared__ float Bs[16][68];   // [k][n], 64 n + pad
    int ntiles = (N + 63) >> 6;
    int mt = blockIdx.x / ntiles, nt = blockIdx.x - mt * ntiles;
    int m0 = mt * 32, n0 = nt * 64;
    int tid = threadIdx.x;
    int tx = tid & 15, ty = tid >> 4;          // out: n quad 4, m pair 2
    int am = tid >> 3, ak = (tid & 7) * 2;     // A: 32 rows x 8 float2
    int bk = tid >> 4, bn = (tid & 15) * 4;    // B: 16 k x 16 float4
    float acc[2][4];
#pragma unroll
    for (int i = 0; i < 2; ++i)
#pragma unroll
        for (int j = 0; j < 4; ++j) acc[i][j] = 0.f;

    bool bok = (n0 + bn < N);
    float2 av = *(const float2*)(A + (m0 + am) * K + ak);
    float4 bv = bok ? *(const float4*)(Bw + bk * N + n0 + bn)
                    : make_float4(0.f, 0.f, 0.f, 0.f);

    for (int k0 = 0; k0 < K; k0 += 16) {
        __syncthreads();                 // prior iteration's LDS reads done
        As[ak + 0][am] = av.x;
        As[ak + 1][am] = av.y;
        *(float4*)&Bs[bk][bn] = bv;
        __syncthreads();                 // tile published
        if (k0 + 16 < K) {               // prefetch next tile (overlaps FMA)
            av = *(const float2*)(A + (m0 + am) * K + k0 + 16 + ak);
            bv = bok ? *(const float4*)(Bw + (k0 + 16 + bk) * N + n0 + bn)
                     : make_float4(0.f, 0.f, 0.f, 0.f);
        }
#pragma unroll
        for (int kk = 0; kk < 16; ++kk) {
            float2 a = *(const float2*)&As[kk][ty * 2];
            float4 b = *(const float4*)&Bs[kk][tx * 4];
            acc[0][0] = fmaf(a.x, b.x, acc[0][0]);
            acc[0][1] = fmaf(a.x, b.y, acc[0][1]);
            acc[0][2] = fmaf(a.x, b.z, acc[0][2]);
            acc[0][3] = fmaf(a.x, b.w, acc[0][3]);
            acc[1][0] = fmaf(a.y, b.x, acc[1][0]);
            acc[1][1] = fmaf(a.y, b.y, acc[1][1]);
            acc[1][2] = fmaf(a.y, b.z, acc[1][2]);
            acc[1][3] = fmaf(a.y, b.w, acc[1][3]);
        }
    }
#pragma unroll
    for (int i = 0; i < 2; ++i) {
        int m = m0 + ty * 2 + i;
#pragma unroll
        for (int j = 0; j < 4; ++j) {
            int n = n0 + tx * 4 + j;
            if (n < N) {
                float v = acc[i][j] + bias[n];
                if (ACT == 0) v = fmaxf(v, 0.f);
                else          v = 1.f / (1.f + expf(-v));
                C[m * N + n] = v;
            }
        }
    }
}

// --------------------------------------------------------------------------
extern "C" void kernel_launch(void* const* d_in, const int* in_sizes, int n_in,
                              void* d_out, int out_size, void* d_ws, size_t ws_size,
                              hipStream_t stream) {
    const float* x   = (const float*)d_in[0];
    const float* w1  = (const float*)d_in[1];
    const float* b1  = (const float*)d_in[2];
    const float* pw  = (const float*)d_in[3];
    const float* pb  = (const float*)d_in[4];
    const float* rw  = (const float*)d_in[5];
    const float* dw1 = (const float*)d_in[6];
    const float* db1 = (const float*)d_in[7];
    const float* dw2 = (const float*)d_in[8];
    const float* db2 = (const float*)d_in[9];
    const float* dw3 = (const float*)d_in[10];
    const float* db3 = (const float*)d_in[11];
    float* out = (float*)d_out;
    char* wsb  = (char*)d_ws;
    if (ws_size < (size_t)WS_BYTES) return;

    h16*   hhi  = (h16*)(wsb + OFFB_HHI);
    h16*   wthi = (h16*)(wsb + OFFB_WTHI);
    h16*   w1t  = (h16*)(wsb + OFFB_WT1);
    float* Cbuf = (float*)(wsb + OFFB_C);
    h16*   pri  = (h16*)(wsb + OFFB_PRI);
    h16*   ut   = (h16*)(wsb + OFFB_UT);
    float* vbuf = (float*)(wsb + OFFB_V);
    float* d1   = (float*)(wsb + OFFB_D1);
    float* d2   = (float*)(wsb + OFFB_D2);

    prep_k<<<1504, 256, 0, stream>>>(w1, pw, w1t, wthi, Cbuf);
    conv1_mfma<<<3200, 256, 0, stream>>>(x, w1t, b1, hhi);
    prim_gemm_mfma<<<2304, 256, 0, stream>>>(hhi, wthi, Cbuf);
    squash_k<<<2304, 256, 0, stream>>>(Cbuf, pb, ut); // h region dead now
    priors_k<<<1440, 256, 0, stream>>>(ut, rw, pri);
    routing2_k<<<5120, 384, 0, stream>>>(pri, vbuf);
    dec1_k<<<512, 512, 0, stream>>>(vbuf, dw1, db1, out, d1);
    dec_gemm<0><<<256, 256, 0, stream>>>(d1, dw2, db2, d2, 512, 1024, 512);
    dec_gemm<1><<<208, 256, 0, stream>>>(d2, dw3, db3, out + 5120, 512, 784, 1024);
}